// Round 5
// baseline (413.470 us; speedup 1.0000x reference)
//
#include <hip/hip_runtime.h>
#include <hip/hip_bf16.h>

#define DIN  128
#define DHID 128
#define DOUT 64

typedef short short8 __attribute__((ext_vector_type(8)));
typedef float f32x4  __attribute__((ext_vector_type(4)));

__device__ __forceinline__ ushort f2bf(float f) {
    union { float f; uint u; } c; c.f = f;
    uint u = c.u;
    return (ushort)((u + 0x7fff + ((u >> 16) & 1)) >> 16);   // RNE
}
__device__ __forceinline__ float bf2f(uint h16) {
    union { uint u; float f; } c; c.u = h16 << 16;
    return c.f;
}

// ---------------------------------------------------------------------------
// Batched prep: [count | cvt_bf16 | prep_w x3] — independent work, one dispatch.
// ---------------------------------------------------------------------------
__device__ __forceinline__ void prep_w_dev(const float* __restrict__ Wself,
                                           const float* __restrict__ Wneigh,
                                           ushort* __restrict__ Wt, int BN, int idx) {
    int k = idx & 255;
    int n = idx >> 8;
    float v = (k < 128) ? Wself[(size_t)k * BN + n] : Wneigh[(size_t)(k - 128) * BN + n];
    Wt[idx] = f2bf(v);
}

__global__ __launch_bounds__(256)
void prep_all(const int* __restrict__ dst, int* __restrict__ cnt, int E, int countB,
              const float* __restrict__ x, ushort* __restrict__ xb, int n4, int cvtB,
              const float* __restrict__ Ws1, const float* __restrict__ Wn1, ushort* __restrict__ Wt1,
              const float* __restrict__ Ws2, const float* __restrict__ Wn2, ushort* __restrict__ Wt2,
              const float* __restrict__ Ws3, const float* __restrict__ Wn3, ushort* __restrict__ Wt3) {
    int b = blockIdx.x;
    if (b < countB) {
        int e = b * 256 + threadIdx.x;
        if (e < E) atomicAdd(&cnt[dst[e]], 1);
        return;
    }
    b -= countB;
    if (b < cvtB) {
        int i = b * 256 + threadIdx.x;
        if (i < n4) {
            float4 v = ((const float4*)x)[i];
            ushort4 o;
            o.x = f2bf(v.x); o.y = f2bf(v.y); o.z = f2bf(v.z); o.w = f2bf(v.w);
            ((ushort4*)xb)[i] = o;
        }
        return;
    }
    b -= cvtB;
    if (b < 128) { prep_w_dev(Ws1, Wn1, Wt1, 128, b * 256 + threadIdx.x); return; }
    b -= 128;
    if (b < 128) { prep_w_dev(Ws2, Wn2, Wt2, 128, b * 256 + threadIdx.x); return; }
    b -= 128;
    prep_w_dev(Ws3, Wn3, Wt3, 64, b * 256 + threadIdx.x);
}

// ---------------------------------------------------------------------------
// CSR scan (multi-block) + fill
// ---------------------------------------------------------------------------
__global__ __launch_bounds__(256)
void scan_part(const int* __restrict__ cnt, int* __restrict__ bsum, int n) {
    __shared__ int red[256];
    int t = threadIdx.x;
    int i = blockIdx.x * 512 + t;
    int v = (i < n) ? cnt[i] : 0;
    if (i + 256 < n) v += cnt[i + 256];
    red[t] = v;
    __syncthreads();
    for (int o = 128; o > 0; o >>= 1) {
        if (t < o) red[t] += red[t + o];
        __syncthreads();
    }
    if (t == 0) bsum[blockIdx.x] = red[0];
}

__global__ __launch_bounds__(128)
void scan_top(int* __restrict__ bsum, int nb, int* __restrict__ row_ptr, int n) {
    __shared__ int s[128];
    int t = threadIdx.x;
    int v = (t < nb) ? bsum[t] : 0;
    s[t] = v;
    __syncthreads();
    for (int o = 1; o < 128; o <<= 1) {
        int u = (t >= o) ? s[t - o] : 0;
        __syncthreads();
        s[t] += u;
        __syncthreads();
    }
    if (t < nb) bsum[t] = s[t] - v;      // exclusive
    if (t == 127) row_ptr[n] = s[127];   // total
}

__global__ __launch_bounds__(256)
void scan_final(const int* __restrict__ cnt, const int* __restrict__ bsum,
                int* __restrict__ row_ptr, int n) {
    __shared__ int s[256];
    int t = threadIdx.x;
    int i0 = blockIdx.x * 512 + t * 2;
    int c0 = (i0 < n) ? cnt[i0] : 0;
    int c1 = (i0 + 1 < n) ? cnt[i0 + 1] : 0;
    s[t] = c0 + c1;
    __syncthreads();
    for (int o = 1; o < 256; o <<= 1) {
        int u = (t >= o) ? s[t - o] : 0;
        __syncthreads();
        s[t] += u;
        __syncthreads();
    }
    int pre = bsum[blockIdx.x] + ((t > 0) ? s[t - 1] : 0);
    if (i0 < n) row_ptr[i0] = pre;
    if (i0 + 1 < n) row_ptr[i0 + 1] = pre + c0;
}

__global__ void fill_kernel(const int* __restrict__ src, const int* __restrict__ dst,
                            const int* __restrict__ row_ptr, int* __restrict__ fill,
                            int* __restrict__ esrc, int E) {
    int e = blockIdx.x * 256 + threadIdx.x;
    if (e < E) {
        int d = dst[e];
        int pos = row_ptr[d] + atomicAdd(&fill[d], 1);
        esrc[pos] = src[e];
    }
}

// ---------------------------------------------------------------------------
// Fused layer, 512 threads, block = 32 nodes:
//   Phase 1: one node per quarter-wave (16 lanes x 16B = 256B row), edge loop
//            unrolled x8 -> 8KB in flight per wave. Lane owns 8 channels.
//   Phase 2: dual GEMM [A_self | A_agg] @ Wt (K=256), 8 waves:
//            wave = (mt: 2 row-halves) x (nq: 4 col-quarters).
// ---------------------------------------------------------------------------
template<int BN, bool FINAL>
__global__ __launch_bounds__(512)
void sage_fused(const ushort* __restrict__ hb,      // [n][128] bf16
                const int* __restrict__ row_ptr, const int* __restrict__ esrc,
                const ushort* __restrict__ Wt,      // [BN][256] bf16
                const float* __restrict__ bias, const float* __restrict__ mask,
                void* __restrict__ outv, int n) {
    constexpr int NT2 = BN / 64;       // n-tiles per wave: 2 (BN=128) or 1
    constexpr int STR = 136;           // LDS row stride in ushorts (272B)
    __shared__ ushort agg_s[32 * STR];

    const int tid  = threadIdx.x;
    const int lane = tid & 63;
    const int wave = tid >> 6;         // 0..7
    const int base = blockIdx.x * 32;
    const int qw   = lane >> 4;        // quarter-wave id 0..3
    const int l16  = lane & 15;

    // ---- Phase 1: one node per quarter-wave ----
    {
        const int local = wave * 4 + qw;       // 0..31
        const int node = base + local;
        if (node < n) {
            const int s = row_ptr[node];
            const int e = row_ptr[node + 1];
            const ushort* __restrict__ hbl = hb + l16 * 8;
            float af[8];
#pragma unroll
            for (int k = 0; k < 8; ++k) af[k] = 0.f;
            int i = s;
            for (; i + 7 < e; i += 8) {        // 8 gathers in flight
                uint4 v[8];
#pragma unroll
                for (int k = 0; k < 8; ++k)
                    v[k] = *(const uint4*)&hbl[(size_t)esrc[i + k] * 128];
#pragma unroll
                for (int k = 0; k < 8; ++k) {
                    af[0] += bf2f(v[k].x & 0xffffu); af[1] += bf2f(v[k].x >> 16);
                    af[2] += bf2f(v[k].y & 0xffffu); af[3] += bf2f(v[k].y >> 16);
                    af[4] += bf2f(v[k].z & 0xffffu); af[5] += bf2f(v[k].z >> 16);
                    af[6] += bf2f(v[k].w & 0xffffu); af[7] += bf2f(v[k].w >> 16);
                }
            }
            for (; i < e; ++i) {
                uint4 v = *(const uint4*)&hbl[(size_t)esrc[i] * 128];
                af[0] += bf2f(v.x & 0xffffu); af[1] += bf2f(v.x >> 16);
                af[2] += bf2f(v.y & 0xffffu); af[3] += bf2f(v.y >> 16);
                af[4] += bf2f(v.z & 0xffffu); af[5] += bf2f(v.z >> 16);
                af[6] += bf2f(v.w & 0xffffu); af[7] += bf2f(v.w >> 16);
            }
            float inv = 1.f / fmaxf((float)(e - s), 1.f);
            uint4 pk;
            pk.x = (uint)f2bf(af[0] * inv) | ((uint)f2bf(af[1] * inv) << 16);
            pk.y = (uint)f2bf(af[2] * inv) | ((uint)f2bf(af[3] * inv) << 16);
            pk.z = (uint)f2bf(af[4] * inv) | ((uint)f2bf(af[5] * inv) << 16);
            pk.w = (uint)f2bf(af[6] * inv) | ((uint)f2bf(af[7] * inv) << 16);
            *(uint4*)&agg_s[local * STR + l16 * 8] = pk;
        }
    }
    __syncthreads();

    // ---- Phase 2: dual GEMM ----
    const int m16 = lane & 15;         // A row / B row / D col within tile
    const int kb  = lane >> 4;         // 0..3 k-block; D row quad
    const int mt  = wave & 1;          // m-tile (2 x 16 rows)
    const int nq  = wave >> 1;         // 0..3 col-quarter
    const int nb  = nq * (BN / 4);

    int arow = base + mt * 16 + m16;
    if (arow >= n) arow = n - 1;       // clamp; stores guarded below
    const ushort* __restrict__ aself = &hb[(size_t)arow * 128 + kb * 8];
    const ushort* __restrict__ alds  = &agg_s[(mt * 16 + m16) * STR + kb * 8];

    f32x4 acc[NT2];
#pragma unroll
    for (int t = 0; t < NT2; ++t) acc[t] = (f32x4)(0.f);

#pragma unroll
    for (int c = 0; c < 8; ++c) {      // 8 k-chunks of 32
        short8 a;
        if (c < 4) a = *(const short8*)(aself + c * 32);
        else       a = *(const short8*)(alds + (c - 4) * 32);
#pragma unroll
        for (int t = 0; t < NT2; ++t) {
            short8 b = *(const short8*)&Wt[(size_t)(nb + t * 16 + m16) * 256 + c * 32 + kb * 8];
            acc[t] = __builtin_amdgcn_mfma_f32_16x16x32_bf16(a, b, acc[t], 0, 0, 0);
        }
    }

    // ---- Epilogue: D col = lane&15, row = (lane>>4)*4 + reg ----
#pragma unroll
    for (int t = 0; t < NT2; ++t) {
        const int col = nb + t * 16 + m16;
        const float bcol = bias[col];
#pragma unroll
        for (int r = 0; r < 4; ++r) {
            const int grow = base + mt * 16 + kb * 4 + r;
            if (grow >= n) continue;
            float z = acc[t][r] + bcol;
            if (!FINAL) {
                z = fmaxf(z, 0.f) * mask[(size_t)grow * 128 + col];
                ((ushort*)outv)[(size_t)grow * 128 + col] = f2bf(z);
            } else {
                ((float*)outv)[(size_t)grow * 64 + col] = z;
            }
        }
    }
}

// ---------------------------------------------------------------------------
extern "C" void kernel_launch(void* const* d_in, const int* in_sizes, int n_in,
                              void* d_out, int out_size, void* d_ws, size_t ws_size,
                              hipStream_t stream) {
    const float* x   = (const float*)d_in[0];
    const int*   src = (const int*)d_in[1];
    const int*   dst = (const int*)d_in[2];
    const float* Ws1 = (const float*)d_in[3];
    const float* Wn1 = (const float*)d_in[4];
    const float* b1  = (const float*)d_in[5];
    const float* Ws2 = (const float*)d_in[6];
    const float* Wn2 = (const float*)d_in[7];
    const float* b2  = (const float*)d_in[8];
    const float* Ws3 = (const float*)d_in[9];
    const float* Wn3 = (const float*)d_in[10];
    const float* b3  = (const float*)d_in[11];
    const float* mask1 = (const float*)d_in[12];
    const float* mask2 = (const float*)d_in[13];
    float* out = (float*)d_out;

    const int N = in_sizes[0] / DIN;
    const int E = in_sizes[1];

    // Workspace layout
    char* ws = (char*)d_ws;
    int* cnt     = (int*)ws;                    // N
    int* fill    = cnt + N;                     // N
    int* row_ptr = fill + N;                    // N+1
    int* esrc    = row_ptr + (N + 1);           // E
    int* bsum    = esrc + E;                    // 128
    size_t off = ((size_t)(3 * N + 1 + E + 128) * sizeof(int) + 255) & ~(size_t)255;
    ushort* xb   = (ushort*)(ws + off);  off += (size_t)N * 128 * 2;
    ushort* h1b  = (ushort*)(ws + off);  off += (size_t)N * 128 * 2;
    ushort* h2b  = (ushort*)(ws + off);  off += (size_t)N * 128 * 2;
    ushort* Wt1  = (ushort*)(ws + off);  off += 256 * 128 * 2;
    ushort* Wt2  = (ushort*)(ws + off);  off += 256 * 128 * 2;
    ushort* Wt3  = (ushort*)(ws + off);  off += 256 * 64 * 2;

    const int nb = (N + 511) / 512;             // 98 for N=50000 (<=128)
    const int countB = (E + 255) / 256;
    const int n4 = N * 128 / 4;
    const int cvtB = (n4 + 255) / 256;

    // --- Prep (count + cvt + weight transpose, one dispatch) ---
    hipMemsetAsync(cnt, 0, (size_t)2 * N * sizeof(int), stream); // cnt + fill
    prep_all<<<countB + cvtB + 320, 256, 0, stream>>>(
        dst, cnt, E, countB, x, xb, n4, cvtB,
        Ws1, Wn1, Wt1, Ws2, Wn2, Wt2, Ws3, Wn3, Wt3);
    // --- CSR scan + fill ---
    scan_part<<<nb, 256, 0, stream>>>(cnt, bsum, N);
    scan_top<<<1, 128, 0, stream>>>(bsum, nb, row_ptr, N);
    scan_final<<<nb, 256, 0, stream>>>(cnt, bsum, row_ptr, N);
    fill_kernel<<<countB, 256, 0, stream>>>(src, dst, row_ptr, fill, esrc, E);

    const int blocks = (N + 31) / 32;

    sage_fused<128, false><<<blocks, 512, 0, stream>>>(xb,  row_ptr, esrc, Wt1, b1, mask1, h1b, N);
    sage_fused<128, false><<<blocks, 512, 0, stream>>>(h1b, row_ptr, esrc, Wt2, b2, mask2, h2b, N);
    sage_fused<64,  true ><<<blocks, 512, 0, stream>>>(h2b, row_ptr, esrc, Wt3, b3, nullptr, out, N);
}

// Round 6
// 390.693 us; speedup vs baseline: 1.0583x; 1.0583x over previous
//
#include <hip/hip_runtime.h>
#include <hip/hip_bf16.h>

#define DIN  128
#define DHID 128
#define DOUT 64

typedef short short8 __attribute__((ext_vector_type(8)));
typedef float f32x4  __attribute__((ext_vector_type(4)));

__device__ __forceinline__ ushort f2bf(float f) {
    union { float f; uint u; } c; c.f = f;
    uint u = c.u;
    return (ushort)((u + 0x7fff + ((u >> 16) & 1)) >> 16);   // RNE
}
__device__ __forceinline__ float bf2f(uint h16) {
    union { uint u; float f; } c; c.u = h16 << 16;
    return c.f;
}
// signed byte k of packed uint -> float
__device__ __forceinline__ float sb8(uint u, int k) {
    return (float)((int)(u << (24 - 8 * k)) >> 24);
}

// ---------------------------------------------------------------------------
// Batched prep: [count | cvt_bf16 | 6x weight transpose] in one dispatch.
// ---------------------------------------------------------------------------
__device__ __forceinline__ void wprep_dev(const float* __restrict__ W,
                                          ushort* __restrict__ Wt, int OUT, int idx) {
    int nn = idx >> 7;
    int k  = idx & 127;
    Wt[idx] = f2bf(W[(size_t)k * OUT + nn]);   // Wt[n][k] = W[k][n]
}

__global__ __launch_bounds__(256)
void prep_all(const int* __restrict__ dst, int* __restrict__ cnt, int E, int countB,
              const float* __restrict__ x, ushort* __restrict__ xb, int n4, int cvtB,
              const float* __restrict__ Ws1, const float* __restrict__ Wn1,
              const float* __restrict__ Ws2, const float* __restrict__ Wn2,
              const float* __restrict__ Ws3, const float* __restrict__ Wn3,
              ushort* __restrict__ Wst1, ushort* __restrict__ Wnt1,
              ushort* __restrict__ Wst2, ushort* __restrict__ Wnt2,
              ushort* __restrict__ Wst3, ushort* __restrict__ Wnt3) {
    int b = blockIdx.x;
    if (b < countB) {
        int e = b * 256 + threadIdx.x;
        if (e < E) atomicAdd(&cnt[dst[e]], 1);
        return;
    }
    b -= countB;
    if (b < cvtB) {
        int i = b * 256 + threadIdx.x;
        if (i < n4) {
            float4 v = ((const float4*)x)[i];
            ushort4 o;
            o.x = f2bf(v.x); o.y = f2bf(v.y); o.z = f2bf(v.z); o.w = f2bf(v.w);
            ((ushort4*)xb)[i] = o;
        }
        return;
    }
    b -= cvtB;
    if (b < 64)  { wprep_dev(Ws1, Wst1, 128, b * 256 + threadIdx.x); return; }
    b -= 64;
    if (b < 64)  { wprep_dev(Wn1, Wnt1, 128, b * 256 + threadIdx.x); return; }
    b -= 64;
    if (b < 64)  { wprep_dev(Ws2, Wst2, 128, b * 256 + threadIdx.x); return; }
    b -= 64;
    if (b < 64)  { wprep_dev(Wn2, Wnt2, 128, b * 256 + threadIdx.x); return; }
    b -= 64;
    if (b < 32)  { wprep_dev(Ws3, Wst3, 64, b * 256 + threadIdx.x); return; }
    b -= 32;
    wprep_dev(Wn3, Wnt3, 64, b * 256 + threadIdx.x);
}

// ---------------------------------------------------------------------------
// CSR scan (multi-block) + fill
// ---------------------------------------------------------------------------
__global__ __launch_bounds__(256)
void scan_part(const int* __restrict__ cnt, int* __restrict__ bsum, int n) {
    __shared__ int red[256];
    int t = threadIdx.x;
    int i = blockIdx.x * 512 + t;
    int v = (i < n) ? cnt[i] : 0;
    if (i + 256 < n) v += cnt[i + 256];
    red[t] = v;
    __syncthreads();
    for (int o = 128; o > 0; o >>= 1) {
        if (t < o) red[t] += red[t + o];
        __syncthreads();
    }
    if (t == 0) bsum[blockIdx.x] = red[0];
}

__global__ __launch_bounds__(128)
void scan_top(int* __restrict__ bsum, int nb, int* __restrict__ row_ptr, int n) {
    __shared__ int s[128];
    int t = threadIdx.x;
    int v = (t < nb) ? bsum[t] : 0;
    s[t] = v;
    __syncthreads();
    for (int o = 1; o < 128; o <<= 1) {
        int u = (t >= o) ? s[t - o] : 0;
        __syncthreads();
        s[t] += u;
        __syncthreads();
    }
    if (t < nb) bsum[t] = s[t] - v;      // exclusive
    if (t == 127) row_ptr[n] = s[127];   // total
}

__global__ __launch_bounds__(256)
void scan_final(const int* __restrict__ cnt, const int* __restrict__ bsum,
                int* __restrict__ row_ptr, int n) {
    __shared__ int s[256];
    int t = threadIdx.x;
    int i0 = blockIdx.x * 512 + t * 2;
    int c0 = (i0 < n) ? cnt[i0] : 0;
    int c1 = (i0 + 1 < n) ? cnt[i0 + 1] : 0;
    s[t] = c0 + c1;
    __syncthreads();
    for (int o = 1; o < 256; o <<= 1) {
        int u = (t >= o) ? s[t - o] : 0;
        __syncthreads();
        s[t] += u;
        __syncthreads();
    }
    int pre = bsum[blockIdx.x] + ((t > 0) ? s[t - 1] : 0);
    if (i0 < n) row_ptr[i0] = pre;
    if (i0 + 1 < n) row_ptr[i0 + 1] = pre + c0;
}

__global__ void fill_kernel(const int* __restrict__ src, const int* __restrict__ dst,
                            const int* __restrict__ row_ptr, int* __restrict__ fill,
                            int* __restrict__ esrc, int E) {
    int e = blockIdx.x * 256 + threadIdx.x;
    if (e < E) {
        int d = dst[e];
        int pos = row_ptr[d] + atomicAdd(&fill[d], 1);
        esrc[pos] = src[e];
    }
}

// ---------------------------------------------------------------------------
// Dense dual GEMM per layer: S = H @ Ws (bf16), G = H @ Wn (int8 + row scale).
// Block = 512 thr = 8 waves = 4 row-groups x {S-wave, G-wave}; 64 rows/block.
// Each wave: 16 rows x OUTW cols, K=128, mfma_f32_16x16x32_bf16.
// G-wave epilogue: 16-lane butterfly max -> per-row scale -> int8 quantize.
// ---------------------------------------------------------------------------
template<int OUTW>
__global__ __launch_bounds__(512)
void sage_gemm(const ushort* __restrict__ Hb,      // [n][128] bf16
               const ushort* __restrict__ Wst,     // [OUTW][128] bf16
               const ushort* __restrict__ Wnt,     // [OUTW][128] bf16
               ushort* __restrict__ S,             // [n][OUTW] bf16
               signed char* __restrict__ Gq,       // [n][OUTW] int8
               float* __restrict__ Gsc,            // [n] fp32
               int n) {
    constexpr int NT = OUTW / 16;                  // 8 or 4
    const int lane = threadIdx.x & 63;
    const int wave = threadIdx.x >> 6;             // 0..7
    const int rg   = wave >> 1;                    // row-group 0..3
    const int isG  = wave & 1;
    const int m16  = lane & 15;
    const int kb   = lane >> 4;                    // 0..3
    const int rbase = blockIdx.x * 64 + rg * 16;

    int arow = rbase + m16; if (arow >= n) arow = n - 1;
    const ushort* __restrict__ Ap = &Hb[(size_t)arow * 128 + kb * 8];
    const ushort* __restrict__ Wt = isG ? Wnt : Wst;

    f32x4 acc[NT];
#pragma unroll
    for (int t = 0; t < NT; ++t) acc[t] = (f32x4)(0.f);

#pragma unroll
    for (int c = 0; c < 4; ++c) {                  // K = 4 x 32
        short8 a = *(const short8*)(Ap + c * 32);
#pragma unroll
        for (int t = 0; t < NT; ++t) {
            short8 b = *(const short8*)&Wt[(size_t)(t * 16 + m16) * 128 + c * 32 + kb * 8];
            acc[t] = __builtin_amdgcn_mfma_f32_16x16x32_bf16(a, b, acc[t], 0, 0, 0);
        }
    }

    // D layout: col = t*16 + m16, row = kb*4 + r
    if (!isG) {
#pragma unroll
        for (int r = 0; r < 4; ++r) {
            int row = rbase + kb * 4 + r;
            if (row >= n) continue;
#pragma unroll
            for (int t = 0; t < NT; ++t)
                S[(size_t)row * OUTW + t * 16 + m16] = f2bf(acc[t][r]);
        }
    } else {
#pragma unroll
        for (int r = 0; r < 4; ++r) {
            float mx = 0.f;
#pragma unroll
            for (int t = 0; t < NT; ++t) mx = fmaxf(mx, fabsf(acc[t][r]));
            mx = fmaxf(mx, __shfl_xor(mx, 1));
            mx = fmaxf(mx, __shfl_xor(mx, 2));
            mx = fmaxf(mx, __shfl_xor(mx, 4));
            mx = fmaxf(mx, __shfl_xor(mx, 8));     // all 16 lanes now hold row max
            int row = rbase + kb * 4 + r;
            if (row >= n) continue;
            float inv = (mx > 0.f) ? 127.f / mx : 0.f;
            if (m16 == 0) Gsc[row] = mx * (1.f / 127.f);
#pragma unroll
            for (int t = 0; t < NT; ++t) {
                int q = (int)rintf(acc[t][r] * inv);
                q = max(-127, min(127, q));
                Gq[(size_t)row * OUTW + t * 16 + m16] = (signed char)q;
            }
        }
    }
}

// ---------------------------------------------------------------------------
// Gather-mean over int8 G rows + epilogue:
//   h = relu(S[node] + mean_agg(G)[node] + b) * mask   (or fp32 out, FINAL)
// Quarter-wave (16 lanes) per node, 2 nodes serial, edge loop unrolled x4.
// Row = OUTW int8 = 128B (uint2/lane) or 64B (uint/lane).
// ---------------------------------------------------------------------------
__device__ __forceinline__ void acc8(float* af, uint2 v, float sc) {
    af[0] += sc * sb8(v.x, 0); af[1] += sc * sb8(v.x, 1);
    af[2] += sc * sb8(v.x, 2); af[3] += sc * sb8(v.x, 3);
    af[4] += sc * sb8(v.y, 0); af[5] += sc * sb8(v.y, 1);
    af[6] += sc * sb8(v.y, 2); af[7] += sc * sb8(v.y, 3);
}
__device__ __forceinline__ void acc4(float* af, uint v, float sc) {
    af[0] += sc * sb8(v, 0); af[1] += sc * sb8(v, 1);
    af[2] += sc * sb8(v, 2); af[3] += sc * sb8(v, 3);
}

template<int OUTW, bool FINAL>
__global__ __launch_bounds__(256)
void sage_gather(const signed char* __restrict__ Gq, const float* __restrict__ Gsc,
                 const ushort* __restrict__ S, const float* __restrict__ bias,
                 const float* __restrict__ mask,
                 const int* __restrict__ row_ptr, const int* __restrict__ esrc,
                 void* __restrict__ outv, int n) {
    const int lane = threadIdx.x & 63;
    const int wave = threadIdx.x >> 6;     // 0..3
    const int qw   = lane >> 4;
    const int l16  = lane & 15;

#pragma unroll
    for (int j = 0; j < 2; ++j) {
        const int node = blockIdx.x * 32 + (wave * 4 + qw) * 2 + j;
        if (node >= n) continue;
        const int s = row_ptr[node];
        const int e = row_ptr[node + 1];
        const float inv = 1.f / fmaxf((float)(e - s), 1.f);

        if (OUTW == 128) {
            const signed char* __restrict__ gp = Gq + l16 * 8;
            float af[8] = {0.f, 0.f, 0.f, 0.f, 0.f, 0.f, 0.f, 0.f};
            int i = s;
            for (; i + 3 < e; i += 4) {
                int n0 = esrc[i], n1 = esrc[i + 1], n2 = esrc[i + 2], n3 = esrc[i + 3];
                uint2 v0 = *(const uint2*)&gp[(size_t)n0 * 128];
                uint2 v1 = *(const uint2*)&gp[(size_t)n1 * 128];
                uint2 v2 = *(const uint2*)&gp[(size_t)n2 * 128];
                uint2 v3 = *(const uint2*)&gp[(size_t)n3 * 128];
                float c0 = Gsc[n0], c1 = Gsc[n1], c2 = Gsc[n2], c3 = Gsc[n3];
                acc8(af, v0, c0); acc8(af, v1, c1); acc8(af, v2, c2); acc8(af, v3, c3);
            }
            for (; i < e; ++i) {
                int ns = esrc[i];
                uint2 v = *(const uint2*)&gp[(size_t)ns * 128];
                acc8(af, v, Gsc[ns]);
            }
            const int col0 = l16 * 8;
            uint4 sv = *(const uint4*)&S[(size_t)node * 128 + col0];
            float4 b0 = *(const float4*)&bias[col0];
            float4 b1 = *(const float4*)&bias[col0 + 4];
            float z[8];
            z[0] = bf2f(sv.x & 0xffffu) + af[0] * inv + b0.x;
            z[1] = bf2f(sv.x >> 16)     + af[1] * inv + b0.y;
            z[2] = bf2f(sv.y & 0xffffu) + af[2] * inv + b0.z;
            z[3] = bf2f(sv.y >> 16)     + af[3] * inv + b0.w;
            z[4] = bf2f(sv.z & 0xffffu) + af[4] * inv + b1.x;
            z[5] = bf2f(sv.z >> 16)     + af[5] * inv + b1.y;
            z[6] = bf2f(sv.w & 0xffffu) + af[6] * inv + b1.z;
            z[7] = bf2f(sv.w >> 16)     + af[7] * inv + b1.w;
            float4 m0 = *(const float4*)&mask[(size_t)node * 128 + col0];
            float4 m1 = *(const float4*)&mask[(size_t)node * 128 + col0 + 4];
            z[0] = fmaxf(z[0], 0.f) * m0.x; z[1] = fmaxf(z[1], 0.f) * m0.y;
            z[2] = fmaxf(z[2], 0.f) * m0.z; z[3] = fmaxf(z[3], 0.f) * m0.w;
            z[4] = fmaxf(z[4], 0.f) * m1.x; z[5] = fmaxf(z[5], 0.f) * m1.y;
            z[6] = fmaxf(z[6], 0.f) * m1.z; z[7] = fmaxf(z[7], 0.f) * m1.w;
            uint4 pk;
            pk.x = (uint)f2bf(z[0]) | ((uint)f2bf(z[1]) << 16);
            pk.y = (uint)f2bf(z[2]) | ((uint)f2bf(z[3]) << 16);
            pk.z = (uint)f2bf(z[4]) | ((uint)f2bf(z[5]) << 16);
            pk.w = (uint)f2bf(z[6]) | ((uint)f2bf(z[7]) << 16);
            *(uint4*)&((ushort*)outv)[(size_t)node * 128 + col0] = pk;
        } else {  // OUTW == 64, FINAL: fp32 out, no relu/mask
            const signed char* __restrict__ gp = Gq + l16 * 4;
            float af[4] = {0.f, 0.f, 0.f, 0.f};
            int i = s;
            for (; i + 3 < e; i += 4) {
                int n0 = esrc[i], n1 = esrc[i + 1], n2 = esrc[i + 2], n3 = esrc[i + 3];
                uint v0 = *(const uint*)&gp[(size_t)n0 * 64];
                uint v1 = *(const uint*)&gp[(size_t)n1 * 64];
                uint v2 = *(const uint*)&gp[(size_t)n2 * 64];
                uint v3 = *(const uint*)&gp[(size_t)n3 * 64];
                float c0 = Gsc[n0], c1 = Gsc[n1], c2 = Gsc[n2], c3 = Gsc[n3];
                acc4(af, v0, c0); acc4(af, v1, c1); acc4(af, v2, c2); acc4(af, v3, c3);
            }
            for (; i < e; ++i) {
                int ns = esrc[i];
                uint v = *(const uint*)&gp[(size_t)ns * 64];
                acc4(af, v, Gsc[ns]);
            }
            const int col0 = l16 * 4;
            uint2 sv = *(const uint2*)&S[(size_t)node * 64 + col0];
            float4 b0 = *(const float4*)&bias[col0];
            float4 z;
            z.x = bf2f(sv.x & 0xffffu) + af[0] * inv + b0.x;
            z.y = bf2f(sv.x >> 16)     + af[1] * inv + b0.y;
            z.z = bf2f(sv.y & 0xffffu) + af[2] * inv + b0.z;
            z.w = bf2f(sv.y >> 16)     + af[3] * inv + b0.w;
            *(float4*)&((float*)outv)[(size_t)node * 64 + col0] = z;
        }
    }
}

// ---------------------------------------------------------------------------
extern "C" void kernel_launch(void* const* d_in, const int* in_sizes, int n_in,
                              void* d_out, int out_size, void* d_ws, size_t ws_size,
                              hipStream_t stream) {
    const float* x   = (const float*)d_in[0];
    const int*   src = (const int*)d_in[1];
    const int*   dst = (const int*)d_in[2];
    const float* Ws1 = (const float*)d_in[3];
    const float* Wn1 = (const float*)d_in[4];
    const float* b1  = (const float*)d_in[5];
    const float* Ws2 = (const float*)d_in[6];
    const float* Wn2 = (const float*)d_in[7];
    const float* b2  = (const float*)d_in[8];
    const float* Ws3 = (const float*)d_in[9];
    const float* Wn3 = (const float*)d_in[10];
    const float* b3  = (const float*)d_in[11];
    const float* mask1 = (const float*)d_in[12];
    const float* mask2 = (const float*)d_in[13];
    float* out = (float*)d_out;

    const int N = in_sizes[0] / DIN;
    const int E = in_sizes[1];

    // Workspace layout
    char* ws = (char*)d_ws;
    int* cnt     = (int*)ws;                    // N
    int* fill    = cnt + N;                     // N
    int* row_ptr = fill + N;                    // N+1
    int* esrc    = row_ptr + (N + 1);           // E
    int* bsum    = esrc + E;                    // 128
    size_t off = ((size_t)(3 * N + 1 + E + 128) * sizeof(int) + 255) & ~(size_t)255;
    ushort* xb   = (ushort*)(ws + off);  off += (size_t)N * 128 * 2;
    ushort* h1b  = (ushort*)(ws + off);  off += (size_t)N * 128 * 2;
    ushort* h2b  = (ushort*)(ws + off);  off += (size_t)N * 128 * 2;
    ushort* S    = (ushort*)(ws + off);  off += (size_t)N * 128 * 2;
    signed char* Gq = (signed char*)(ws + off); off += (size_t)N * 128;
    float* Gsc   = (float*)(ws + off);   off += (size_t)N * 4;
    ushort* Wst1 = (ushort*)(ws + off);  off += 128 * 128 * 2;
    ushort* Wnt1 = (ushort*)(ws + off);  off += 128 * 128 * 2;
    ushort* Wst2 = (ushort*)(ws + off);  off += 128 * 128 * 2;
    ushort* Wnt2 = (ushort*)(ws + off);  off += 128 * 128 * 2;
    ushort* Wst3 = (ushort*)(ws + off);  off += 64 * 128 * 2;
    ushort* Wnt3 = (ushort*)(ws + off);  off += 64 * 128 * 2;

    const int nb = (N + 511) / 512;             // 98 (<=128)
    const int countB = (E + 255) / 256;
    const int n4 = N * 128 / 4;
    const int cvtB = (n4 + 255) / 256;

    // --- Prep (count + cvt + weight transposes, one dispatch) ---
    hipMemsetAsync(cnt, 0, (size_t)2 * N * sizeof(int), stream); // cnt + fill
    prep_all<<<countB + cvtB + 4 * 64 + 2 * 32, 256, 0, stream>>>(
        dst, cnt, E, countB, x, xb, n4, cvtB,
        Ws1, Wn1, Ws2, Wn2, Ws3, Wn3,
        Wst1, Wnt1, Wst2, Wnt2, Wst3, Wnt3);
    // --- CSR scan + fill ---
    scan_part<<<nb, 256, 0, stream>>>(cnt, bsum, N);
    scan_top<<<1, 128, 0, stream>>>(bsum, nb, row_ptr, N);
    scan_final<<<nb, 256, 0, stream>>>(cnt, bsum, row_ptr, N);
    fill_kernel<<<countB, 256, 0, stream>>>(src, dst, row_ptr, fill, esrc, E);

    const int gemmB = (N + 63) / 64;
    const int gathB = (N + 31) / 32;

    // --- Layer 1 ---
    sage_gemm<128><<<gemmB, 512, 0, stream>>>(xb, Wst1, Wnt1, S, Gq, Gsc, N);
    sage_gather<128, false><<<gathB, 256, 0, stream>>>(Gq, Gsc, S, b1, mask1, row_ptr, esrc, h1b, N);
    // --- Layer 2 ---
    sage_gemm<128><<<gemmB, 512, 0, stream>>>(h1b, Wst2, Wnt2, S, Gq, Gsc, N);
    sage_gather<128, false><<<gathB, 256, 0, stream>>>(Gq, Gsc, S, b2, mask2, row_ptr, esrc, h2b, N);
    // --- Layer 3 ---
    sage_gemm<64><<<gemmB, 512, 0, stream>>>(h2b, Wst3, Wnt3, S, Gq, Gsc, N);
    sage_gather<64, true><<<gathB, 256, 0, stream>>>(Gq, Gsc, S, b3, nullptr, row_ptr, esrc, out, N);
}

// Round 7
// 351.499 us; speedup vs baseline: 1.1763x; 1.1115x over previous
//
#include <hip/hip_runtime.h>
#include <hip/hip_bf16.h>

#define DIN  128
#define DHID 128
#define DOUT 64

typedef short short8 __attribute__((ext_vector_type(8)));
typedef float f32x4  __attribute__((ext_vector_type(4)));

__device__ __forceinline__ ushort f2bf(float f) {
    union { float f; uint u; } c; c.f = f;
    uint u = c.u;
    return (ushort)((u + 0x7fff + ((u >> 16) & 1)) >> 16);   // RNE
}
__device__ __forceinline__ float bf2f(uint h16) {
    union { uint u; float f; } c; c.u = h16 << 16;
    return c.f;
}
// signed byte k of packed uint -> float
__device__ __forceinline__ float sb8(uint u, int k) {
    return (float)((int)(u << (24 - 8 * k)) >> 24);
}

// ---------------------------------------------------------------------------
// Batched prep: [cvt_bf16 | 6x weight transpose] in one dispatch.
// ---------------------------------------------------------------------------
__device__ __forceinline__ void wprep_dev(const float* __restrict__ W,
                                          ushort* __restrict__ Wt, int OUT, int idx) {
    int nn = idx >> 7;
    int k  = idx & 127;
    Wt[idx] = f2bf(W[(size_t)k * OUT + nn]);   // Wt[n][k] = W[k][n]
}

__global__ __launch_bounds__(256)
void prep_all(const float* __restrict__ x, ushort* __restrict__ xb, int n4, int cvtB,
              const float* __restrict__ Ws1, const float* __restrict__ Wn1,
              const float* __restrict__ Ws2, const float* __restrict__ Wn2,
              const float* __restrict__ Ws3, const float* __restrict__ Wn3,
              ushort* __restrict__ Wst1, ushort* __restrict__ Wnt1,
              ushort* __restrict__ Wst2, ushort* __restrict__ Wnt2,
              ushort* __restrict__ Wst3, ushort* __restrict__ Wnt3) {
    int b = blockIdx.x;
    if (b < cvtB) {
        int i = b * 256 + threadIdx.x;
        if (i < n4) {
            float4 v = ((const float4*)x)[i];
            ushort4 o;
            o.x = f2bf(v.x); o.y = f2bf(v.y); o.z = f2bf(v.z); o.w = f2bf(v.w);
            ((ushort4*)xb)[i] = o;
        }
        return;
    }
    b -= cvtB;
    if (b < 64)  { wprep_dev(Ws1, Wst1, 128, b * 256 + threadIdx.x); return; }
    b -= 64;
    if (b < 64)  { wprep_dev(Wn1, Wnt1, 128, b * 256 + threadIdx.x); return; }
    b -= 64;
    if (b < 64)  { wprep_dev(Ws2, Wst2, 128, b * 256 + threadIdx.x); return; }
    b -= 64;
    if (b < 64)  { wprep_dev(Wn2, Wnt2, 128, b * 256 + threadIdx.x); return; }
    b -= 64;
    if (b < 32)  { wprep_dev(Ws3, Wst3, 64, b * 256 + threadIdx.x); return; }
    b -= 32;
    wprep_dev(Wn3, Wnt3, 64, b * 256 + threadIdx.x);
}

// ---------------------------------------------------------------------------
// Bucketed CSR build. Buckets of 256 dst-nodes (nbkt = ceil(N/256) <= 256).
//   bucket_count: per-block LDS histogram -> 256 global atomics/block.
//   bucket_scan : 1-block exclusive scan of bucket sizes -> base & cursor.
//   bucket_fill : append (src, dst&255) pairs to bucket regions; per-block
//                 per-bucket range reservation -> semi-contiguous writes.
//   bucket_csr  : 1 block/bucket: pairs -> LDS, local count+scan+scatter into
//                 the bucket's CONTIGUOUS esrc region; writes row_ptr.
// ---------------------------------------------------------------------------
#define EB 4096   // edges per block for count/fill

__global__ __launch_bounds__(256)
void bucket_count(const int* __restrict__ dst, int E, int* __restrict__ bkt_cnt) {
    __shared__ int c[256];
    const int t = threadIdx.x;
    c[t] = 0;
    __syncthreads();
    const int base = blockIdx.x * EB;
    const int end = min(base + EB, E);
    for (int i = base + t; i < end; i += 256)
        atomicAdd(&c[dst[i] >> 8], 1);
    __syncthreads();
    int v = c[t];
    if (v) atomicAdd(&bkt_cnt[t], v);
}

__global__ __launch_bounds__(256)
void bucket_scan(const int* __restrict__ bkt_cnt, int nbkt,
                 int* __restrict__ bkt_base, int* __restrict__ bkt_cur) {
    __shared__ int s[256];
    const int t = threadIdx.x;
    int v = (t < nbkt) ? bkt_cnt[t] : 0;
    s[t] = v;
    __syncthreads();
    for (int o = 1; o < 256; o <<= 1) {
        int u = (t >= o) ? s[t - o] : 0;
        __syncthreads();
        s[t] += u;
        __syncthreads();
    }
    if (t < nbkt) { bkt_base[t] = s[t] - v; bkt_cur[t] = s[t] - v; }
}

__global__ __launch_bounds__(256)
void bucket_fill(const int* __restrict__ src, const int* __restrict__ dst, int E,
                 int* __restrict__ bkt_cur, uint2* __restrict__ pairs) {
    __shared__ int c[256];
    __shared__ int startl[256];
    __shared__ int ofs[256];
    const int t = threadIdx.x;
    c[t] = 0;
    __syncthreads();
    const int base = blockIdx.x * EB;
    const int end = min(base + EB, E);
    for (int i = base + t; i < end; i += 256)
        atomicAdd(&c[dst[i] >> 8], 1);
    __syncthreads();
    int v = c[t];
    startl[t] = v ? atomicAdd(&bkt_cur[t], v) : 0;
    ofs[t] = 0;
    __syncthreads();
    for (int i = base + t; i < end; i += 256) {
        int d = dst[i];
        int b = d >> 8;
        int p = startl[b] + atomicAdd(&ofs[b], 1);
        pairs[p] = make_uint2((uint)src[i], (uint)(d & 255));
    }
}

__global__ __launch_bounds__(256)
void bucket_csr(const uint2* __restrict__ pairs, const int* __restrict__ bkt_base,
                const int* __restrict__ bkt_cnt, int* __restrict__ row_ptr,
                int* __restrict__ esrc, int N, int E, int nbkt) {
    constexpr int CAP = 6144;                  // 48 KB of pairs
    __shared__ uint2 pl[CAP];
    __shared__ int cnt[256];
    __shared__ int rs[256];
    __shared__ int sc[256];
    const int bkt = blockIdx.x;
    const int t = threadIdx.x;
    const int ebase = bkt_base[bkt];
    const int ecnt  = bkt_cnt[bkt];
    cnt[t] = 0;
    __syncthreads();
    const bool fits = (ecnt <= CAP);
    if (fits) {
        for (int i = t; i < ecnt; i += 256) {
            uint2 p = pairs[ebase + i];
            pl[i] = p;
            atomicAdd(&cnt[p.y], 1);
        }
    } else {
        for (int i = t; i < ecnt; i += 256)
            atomicAdd(&cnt[pairs[ebase + i].y], 1);
    }
    __syncthreads();
    int own = cnt[t];
    sc[t] = own;
    __syncthreads();
    for (int o = 1; o < 256; o <<= 1) {
        int u = (t >= o) ? sc[t - o] : 0;
        __syncthreads();
        sc[t] += u;
        __syncthreads();
    }
    rs[t] = sc[t] - own;                        // exclusive local start
    const int node = bkt * 256 + t;
    if (node < N) row_ptr[node] = ebase + rs[t];
    if (bkt == nbkt - 1 && t == 0) row_ptr[N] = E;
    __syncthreads();
    if (fits) {
        for (int i = t; i < ecnt; i += 256) {
            uint2 p = pl[i];
            int pos = atomicAdd(&rs[p.y], 1);
            esrc[ebase + pos] = (int)p.x;
        }
    } else {
        for (int i = t; i < ecnt; i += 256) {
            uint2 p = pairs[ebase + i];
            int pos = atomicAdd(&rs[p.y], 1);
            esrc[ebase + pos] = (int)p.x;
        }
    }
}

// ---------------------------------------------------------------------------
// Dense dual GEMM per layer: S = H @ Ws (bf16), G = H @ Wn (int8 + row scale).
// ---------------------------------------------------------------------------
template<int OUTW>
__global__ __launch_bounds__(512)
void sage_gemm(const ushort* __restrict__ Hb,      // [n][128] bf16
               const ushort* __restrict__ Wst,     // [OUTW][128] bf16
               const ushort* __restrict__ Wnt,     // [OUTW][128] bf16
               ushort* __restrict__ S,             // [n][OUTW] bf16
               signed char* __restrict__ Gq,       // [n][OUTW] int8
               float* __restrict__ Gsc,            // [n] fp32
               int n) {
    constexpr int NT = OUTW / 16;                  // 8 or 4
    const int lane = threadIdx.x & 63;
    const int wave = threadIdx.x >> 6;             // 0..7
    const int rg   = wave >> 1;                    // row-group 0..3
    const int isG  = wave & 1;
    const int m16  = lane & 15;
    const int kb   = lane >> 4;                    // 0..3
    const int rbase = blockIdx.x * 64 + rg * 16;

    int arow = rbase + m16; if (arow >= n) arow = n - 1;
    const ushort* __restrict__ Ap = &Hb[(size_t)arow * 128 + kb * 8];
    const ushort* __restrict__ Wt = isG ? Wnt : Wst;

    f32x4 acc[NT];
#pragma unroll
    for (int t = 0; t < NT; ++t) acc[t] = (f32x4)(0.f);

#pragma unroll
    for (int c = 0; c < 4; ++c) {                  // K = 4 x 32
        short8 a = *(const short8*)(Ap + c * 32);
#pragma unroll
        for (int t = 0; t < NT; ++t) {
            short8 b = *(const short8*)&Wt[(size_t)(t * 16 + m16) * 128 + c * 32 + kb * 8];
            acc[t] = __builtin_amdgcn_mfma_f32_16x16x32_bf16(a, b, acc[t], 0, 0, 0);
        }
    }

    // D layout: col = t*16 + m16, row = kb*4 + r
    if (!isG) {
#pragma unroll
        for (int r = 0; r < 4; ++r) {
            int row = rbase + kb * 4 + r;
            if (row >= n) continue;
#pragma unroll
            for (int t = 0; t < NT; ++t)
                S[(size_t)row * OUTW + t * 16 + m16] = f2bf(acc[t][r]);
        }
    } else {
#pragma unroll
        for (int r = 0; r < 4; ++r) {
            float mx = 0.f;
#pragma unroll
            for (int t = 0; t < NT; ++t) mx = fmaxf(mx, fabsf(acc[t][r]));
            mx = fmaxf(mx, __shfl_xor(mx, 1));
            mx = fmaxf(mx, __shfl_xor(mx, 2));
            mx = fmaxf(mx, __shfl_xor(mx, 4));
            mx = fmaxf(mx, __shfl_xor(mx, 8));     // all 16 lanes now hold row max
            int row = rbase + kb * 4 + r;
            if (row >= n) continue;
            float inv = (mx > 0.f) ? 127.f / mx : 0.f;
            if (m16 == 0) Gsc[row] = mx * (1.f / 127.f);
#pragma unroll
            for (int t = 0; t < NT; ++t) {
                int q = (int)rintf(acc[t][r] * inv);
                q = max(-127, min(127, q));
                Gq[(size_t)row * OUTW + t * 16 + m16] = (signed char)q;
            }
        }
    }
}

// ---------------------------------------------------------------------------
// Gather-mean over int8 G rows + epilogue.
// ---------------------------------------------------------------------------
__device__ __forceinline__ void acc8(float* af, uint2 v, float sc) {
    af[0] += sc * sb8(v.x, 0); af[1] += sc * sb8(v.x, 1);
    af[2] += sc * sb8(v.x, 2); af[3] += sc * sb8(v.x, 3);
    af[4] += sc * sb8(v.y, 0); af[5] += sc * sb8(v.y, 1);
    af[6] += sc * sb8(v.y, 2); af[7] += sc * sb8(v.y, 3);
}
__device__ __forceinline__ void acc4(float* af, uint v, float sc) {
    af[0] += sc * sb8(v, 0); af[1] += sc * sb8(v, 1);
    af[2] += sc * sb8(v, 2); af[3] += sc * sb8(v, 3);
}

template<int OUTW, bool FINAL>
__global__ __launch_bounds__(256)
void sage_gather(const signed char* __restrict__ Gq, const float* __restrict__ Gsc,
                 const ushort* __restrict__ S, const float* __restrict__ bias,
                 const float* __restrict__ mask,
                 const int* __restrict__ row_ptr, const int* __restrict__ esrc,
                 void* __restrict__ outv, int n) {
    const int lane = threadIdx.x & 63;
    const int wave = threadIdx.x >> 6;     // 0..3
    const int qw   = lane >> 4;
    const int l16  = lane & 15;

#pragma unroll
    for (int j = 0; j < 2; ++j) {
        const int node = blockIdx.x * 32 + (wave * 4 + qw) * 2 + j;
        if (node >= n) continue;
        const int s = row_ptr[node];
        const int e = row_ptr[node + 1];
        const float inv = 1.f / fmaxf((float)(e - s), 1.f);

        if (OUTW == 128) {
            const signed char* __restrict__ gp = Gq + l16 * 8;
            float af[8] = {0.f, 0.f, 0.f, 0.f, 0.f, 0.f, 0.f, 0.f};
            int i = s;
            for (; i + 3 < e; i += 4) {
                int n0 = esrc[i], n1 = esrc[i + 1], n2 = esrc[i + 2], n3 = esrc[i + 3];
                uint2 v0 = *(const uint2*)&gp[(size_t)n0 * 128];
                uint2 v1 = *(const uint2*)&gp[(size_t)n1 * 128];
                uint2 v2 = *(const uint2*)&gp[(size_t)n2 * 128];
                uint2 v3 = *(const uint2*)&gp[(size_t)n3 * 128];
                float c0 = Gsc[n0], c1 = Gsc[n1], c2 = Gsc[n2], c3 = Gsc[n3];
                acc8(af, v0, c0); acc8(af, v1, c1); acc8(af, v2, c2); acc8(af, v3, c3);
            }
            for (; i < e; ++i) {
                int ns = esrc[i];
                uint2 v = *(const uint2*)&gp[(size_t)ns * 128];
                acc8(af, v, Gsc[ns]);
            }
            const int col0 = l16 * 8;
            uint4 sv = *(const uint4*)&S[(size_t)node * 128 + col0];
            float4 b0 = *(const float4*)&bias[col0];
            float4 b1 = *(const float4*)&bias[col0 + 4];
            float z[8];
            z[0] = bf2f(sv.x & 0xffffu) + af[0] * inv + b0.x;
            z[1] = bf2f(sv.x >> 16)     + af[1] * inv + b0.y;
            z[2] = bf2f(sv.y & 0xffffu) + af[2] * inv + b0.z;
            z[3] = bf2f(sv.y >> 16)     + af[3] * inv + b0.w;
            z[4] = bf2f(sv.z & 0xffffu) + af[4] * inv + b1.x;
            z[5] = bf2f(sv.z >> 16)     + af[5] * inv + b1.y;
            z[6] = bf2f(sv.w & 0xffffu) + af[6] * inv + b1.z;
            z[7] = bf2f(sv.w >> 16)     + af[7] * inv + b1.w;
            float4 m0 = *(const float4*)&mask[(size_t)node * 128 + col0];
            float4 m1 = *(const float4*)&mask[(size_t)node * 128 + col0 + 4];
            z[0] = fmaxf(z[0], 0.f) * m0.x; z[1] = fmaxf(z[1], 0.f) * m0.y;
            z[2] = fmaxf(z[2], 0.f) * m0.z; z[3] = fmaxf(z[3], 0.f) * m0.w;
            z[4] = fmaxf(z[4], 0.f) * m1.x; z[5] = fmaxf(z[5], 0.f) * m1.y;
            z[6] = fmaxf(z[6], 0.f) * m1.z; z[7] = fmaxf(z[7], 0.f) * m1.w;
            uint4 pk;
            pk.x = (uint)f2bf(z[0]) | ((uint)f2bf(z[1]) << 16);
            pk.y = (uint)f2bf(z[2]) | ((uint)f2bf(z[3]) << 16);
            pk.z = (uint)f2bf(z[4]) | ((uint)f2bf(z[5]) << 16);
            pk.w = (uint)f2bf(z[6]) | ((uint)f2bf(z[7]) << 16);
            *(uint4*)&((ushort*)outv)[(size_t)node * 128 + col0] = pk;
        } else {  // OUTW == 64, FINAL: fp32 out, no relu/mask
            const signed char* __restrict__ gp = Gq + l16 * 4;
            float af[4] = {0.f, 0.f, 0.f, 0.f};
            int i = s;
            for (; i + 3 < e; i += 4) {
                int n0 = esrc[i], n1 = esrc[i + 1], n2 = esrc[i + 2], n3 = esrc[i + 3];
                uint v0 = *(const uint*)&gp[(size_t)n0 * 64];
                uint v1 = *(const uint*)&gp[(size_t)n1 * 64];
                uint v2 = *(const uint*)&gp[(size_t)n2 * 64];
                uint v3 = *(const uint*)&gp[(size_t)n3 * 64];
                float c0 = Gsc[n0], c1 = Gsc[n1], c2 = Gsc[n2], c3 = Gsc[n3];
                acc4(af, v0, c0); acc4(af, v1, c1); acc4(af, v2, c2); acc4(af, v3, c3);
            }
            for (; i < e; ++i) {
                int ns = esrc[i];
                uint v = *(const uint*)&gp[(size_t)ns * 64];
                acc4(af, v, Gsc[ns]);
            }
            const int col0 = l16 * 4;
            uint2 sv = *(const uint2*)&S[(size_t)node * 64 + col0];
            float4 b0 = *(const float4*)&bias[col0];
            float4 z;
            z.x = bf2f(sv.x & 0xffffu) + af[0] * inv + b0.x;
            z.y = bf2f(sv.x >> 16)     + af[1] * inv + b0.y;
            z.z = bf2f(sv.y & 0xffffu) + af[2] * inv + b0.z;
            z.w = bf2f(sv.y >> 16)     + af[3] * inv + b0.w;
            *(float4*)&((float*)outv)[(size_t)node * 64 + col0] = z;
        }
    }
}

// ---------------------------------------------------------------------------
extern "C" void kernel_launch(void* const* d_in, const int* in_sizes, int n_in,
                              void* d_out, int out_size, void* d_ws, size_t ws_size,
                              hipStream_t stream) {
    const float* x   = (const float*)d_in[0];
    const int*   src = (const int*)d_in[1];
    const int*   dst = (const int*)d_in[2];
    const float* Ws1 = (const float*)d_in[3];
    const float* Wn1 = (const float*)d_in[4];
    const float* b1  = (const float*)d_in[5];
    const float* Ws2 = (const float*)d_in[6];
    const float* Wn2 = (const float*)d_in[7];
    const float* b2  = (const float*)d_in[8];
    const float* Ws3 = (const float*)d_in[9];
    const float* Wn3 = (const float*)d_in[10];
    const float* b3  = (const float*)d_in[11];
    const float* mask1 = (const float*)d_in[12];
    const float* mask2 = (const float*)d_in[13];
    float* out = (float*)d_out;

    const int N = in_sizes[0] / DIN;
    const int E = in_sizes[1];
    const int nbkt = (N + 255) >> 8;            // 196 for N=50000 (<=256)

    // Workspace layout
    char* ws = (char*)d_ws;
    int* bkt_cnt  = (int*)ws;                   // 256
    int* bkt_base = bkt_cnt + 256;              // 256
    int* bkt_cur  = bkt_base + 256;             // 256
    int* row_ptr  = bkt_cur + 256;              // N+1
    int* esrc     = row_ptr + (N + 1);          // E
    size_t off = ((size_t)(768 + N + 1 + E) * sizeof(int) + 255) & ~(size_t)255;
    uint2* pairs = (uint2*)(ws + off);   off += (size_t)E * 8;
    ushort* xb   = (ushort*)(ws + off);  off += (size_t)N * 128 * 2;
    ushort* h1b  = (ushort*)(ws + off);  off += (size_t)N * 128 * 2;
    ushort* h2b  = (ushort*)(ws + off);  off += (size_t)N * 128 * 2;
    ushort* S    = (ushort*)(ws + off);  off += (size_t)N * 128 * 2;
    signed char* Gq = (signed char*)(ws + off); off += (size_t)N * 128;
    float* Gsc   = (float*)(ws + off);   off += (size_t)N * 4;
    ushort* Wst1 = (ushort*)(ws + off);  off += 128 * 128 * 2;
    ushort* Wnt1 = (ushort*)(ws + off);  off += 128 * 128 * 2;
    ushort* Wst2 = (ushort*)(ws + off);  off += 128 * 128 * 2;
    ushort* Wnt2 = (ushort*)(ws + off);  off += 128 * 128 * 2;
    ushort* Wst3 = (ushort*)(ws + off);  off += 64 * 128 * 2;
    ushort* Wnt3 = (ushort*)(ws + off);  off += 64 * 128 * 2;

    const int n4 = N * 128 / 4;
    const int cvtB = (n4 + 255) / 256;
    const int ebB = (E + EB - 1) / EB;

    // --- Prep (cvt + weight transposes) ---
    hipMemsetAsync(bkt_cnt, 0, 256 * sizeof(int), stream);
    prep_all<<<cvtB + 4 * 64 + 2 * 32, 256, 0, stream>>>(
        x, xb, n4, cvtB,
        Ws1, Wn1, Ws2, Wn2, Ws3, Wn3,
        Wst1, Wnt1, Wst2, Wnt2, Wst3, Wnt3);

    // --- Bucketed CSR build ---
    bucket_count<<<ebB, 256, 0, stream>>>(dst, E, bkt_cnt);
    bucket_scan<<<1, 256, 0, stream>>>(bkt_cnt, nbkt, bkt_base, bkt_cur);
    bucket_fill<<<ebB, 256, 0, stream>>>(src, dst, E, bkt_cur, pairs);
    bucket_csr<<<nbkt, 256, 0, stream>>>(pairs, bkt_base, bkt_cnt, row_ptr, esrc, N, E, nbkt);

    const int gemmB = (N + 63) / 64;
    const int gathB = (N + 31) / 32;

    // --- Layer 1 ---
    sage_gemm<128><<<gemmB, 512, 0, stream>>>(xb, Wst1, Wnt1, S, Gq, Gsc, N);
    sage_gather<128, false><<<gathB, 256, 0, stream>>>(Gq, Gsc, S, b1, mask1, row_ptr, esrc, h1b, N);
    // --- Layer 2 ---
    sage_gemm<128><<<gemmB, 512, 0, stream>>>(h1b, Wst2, Wnt2, S, Gq, Gsc, N);
    sage_gather<128, false><<<gathB, 256, 0, stream>>>(Gq, Gsc, S, b2, mask2, row_ptr, esrc, h2b, N);
    // --- Layer 3 ---
    sage_gemm<64><<<gemmB, 512, 0, stream>>>(h2b, Wst3, Wnt3, S, Gq, Gsc, N);
    sage_gather<64, true><<<gathB, 256, 0, stream>>>(Gq, Gsc, S, b3, nullptr, row_ptr, esrc, out, N);
}

// Round 8
// 304.365 us; speedup vs baseline: 1.3585x; 1.1549x over previous
//
#include <hip/hip_runtime.h>
#include <hip/hip_bf16.h>

#define DIN  128
#define DHID 128
#define DOUT 64

typedef short short8 __attribute__((ext_vector_type(8)));
typedef float f32x4  __attribute__((ext_vector_type(4)));

__device__ __forceinline__ ushort f2bf(float f) {
    union { float f; uint u; } c; c.f = f;
    uint u = c.u;
    return (ushort)((u + 0x7fff + ((u >> 16) & 1)) >> 16);   // RNE
}
__device__ __forceinline__ float bf2f(uint h16) {
    union { uint u; float f; } c; c.u = h16 << 16;
    return c.f;
}
// signed byte k of packed uint -> float
__device__ __forceinline__ float sb8(uint u, int k) {
    return (float)((int)(u << (24 - 8 * k)) >> 24);
}

// ---------------------------------------------------------------------------
// Batched prep: [cvt_bf16 | 6x weight transpose] in one dispatch.
// ---------------------------------------------------------------------------
__device__ __forceinline__ void wprep_dev(const float* __restrict__ W,
                                          ushort* __restrict__ Wt, int OUT, int idx) {
    int nn = idx >> 7;
    int k  = idx & 127;
    Wt[idx] = f2bf(W[(size_t)k * OUT + nn]);   // Wt[n][k] = W[k][n]
}

__global__ __launch_bounds__(256)
void prep_all(const float* __restrict__ x, ushort* __restrict__ xb, int n4, int cvtB,
              const float* __restrict__ Ws1, const float* __restrict__ Wn1,
              const float* __restrict__ Ws2, const float* __restrict__ Wn2,
              const float* __restrict__ Ws3, const float* __restrict__ Wn3,
              ushort* __restrict__ Wst1, ushort* __restrict__ Wnt1,
              ushort* __restrict__ Wst2, ushort* __restrict__ Wnt2,
              ushort* __restrict__ Wst3, ushort* __restrict__ Wnt3) {
    int b = blockIdx.x;
    if (b < cvtB) {
        int i = b * 256 + threadIdx.x;
        if (i < n4) {
            float4 v = ((const float4*)x)[i];
            ushort4 o;
            o.x = f2bf(v.x); o.y = f2bf(v.y); o.z = f2bf(v.z); o.w = f2bf(v.w);
            ((ushort4*)xb)[i] = o;
        }
        return;
    }
    b -= cvtB;
    if (b < 64)  { wprep_dev(Ws1, Wst1, 128, b * 256 + threadIdx.x); return; }
    b -= 64;
    if (b < 64)  { wprep_dev(Wn1, Wnt1, 128, b * 256 + threadIdx.x); return; }
    b -= 64;
    if (b < 64)  { wprep_dev(Ws2, Wst2, 128, b * 256 + threadIdx.x); return; }
    b -= 64;
    if (b < 64)  { wprep_dev(Wn2, Wnt2, 128, b * 256 + threadIdx.x); return; }
    b -= 64;
    if (b < 32)  { wprep_dev(Ws3, Wst3, 64, b * 256 + threadIdx.x); return; }
    b -= 32;
    wprep_dev(Wn3, Wnt3, 64, b * 256 + threadIdx.x);
}

// ---------------------------------------------------------------------------
// Bucketed CSR build (buckets of 256 dst-nodes).
// ---------------------------------------------------------------------------
#define EB 4096   // edges per block for count/fill

__global__ __launch_bounds__(256)
void bucket_count(const int* __restrict__ dst, int E, int* __restrict__ bkt_cnt) {
    __shared__ int c[256];
    const int t = threadIdx.x;
    c[t] = 0;
    __syncthreads();
    const int base = blockIdx.x * EB;
    const int end = min(base + EB, E);
    for (int i = base + t; i < end; i += 256)
        atomicAdd(&c[dst[i] >> 8], 1);
    __syncthreads();
    int v = c[t];
    if (v) atomicAdd(&bkt_cnt[t], v);
}

__global__ __launch_bounds__(256)
void bucket_scan(const int* __restrict__ bkt_cnt, int nbkt,
                 int* __restrict__ bkt_base, int* __restrict__ bkt_cur) {
    __shared__ int s[256];
    const int t = threadIdx.x;
    int v = (t < nbkt) ? bkt_cnt[t] : 0;
    s[t] = v;
    __syncthreads();
    for (int o = 1; o < 256; o <<= 1) {
        int u = (t >= o) ? s[t - o] : 0;
        __syncthreads();
        s[t] += u;
        __syncthreads();
    }
    if (t < nbkt) { bkt_base[t] = s[t] - v; bkt_cur[t] = s[t] - v; }
}

__global__ __launch_bounds__(256)
void bucket_fill(const int* __restrict__ src, const int* __restrict__ dst, int E,
                 int* __restrict__ bkt_cur, uint2* __restrict__ pairs) {
    __shared__ int c[256];
    __shared__ int startl[256];
    __shared__ int ofs[256];
    const int t = threadIdx.x;
    c[t] = 0;
    __syncthreads();
    const int base = blockIdx.x * EB;
    const int end = min(base + EB, E);
    for (int i = base + t; i < end; i += 256)
        atomicAdd(&c[dst[i] >> 8], 1);
    __syncthreads();
    int v = c[t];
    startl[t] = v ? atomicAdd(&bkt_cur[t], v) : 0;
    ofs[t] = 0;
    __syncthreads();
    for (int i = base + t; i < end; i += 256) {
        int d = dst[i];
        int b = d >> 8;
        int p = startl[b] + atomicAdd(&ofs[b], 1);
        pairs[p] = make_uint2((uint)src[i], (uint)(d & 255));
    }
}

__global__ __launch_bounds__(256)
void bucket_csr(const uint2* __restrict__ pairs, const int* __restrict__ bkt_base,
                const int* __restrict__ bkt_cnt, int* __restrict__ row_ptr,
                int* __restrict__ esrc, int N, int E, int nbkt) {
    constexpr int CAP = 6144;                  // 48 KB of pairs
    __shared__ uint2 pl[CAP];
    __shared__ int cnt[256];
    __shared__ int rs[256];
    __shared__ int sc[256];
    const int bkt = blockIdx.x;
    const int t = threadIdx.x;
    const int ebase = bkt_base[bkt];
    const int ecnt  = bkt_cnt[bkt];
    cnt[t] = 0;
    __syncthreads();
    const bool fits = (ecnt <= CAP);
    if (fits) {
        for (int i = t; i < ecnt; i += 256) {
            uint2 p = pairs[ebase + i];
            pl[i] = p;
            atomicAdd(&cnt[p.y], 1);
        }
    } else {
        for (int i = t; i < ecnt; i += 256)
            atomicAdd(&cnt[pairs[ebase + i].y], 1);
    }
    __syncthreads();
    int own = cnt[t];
    sc[t] = own;
    __syncthreads();
    for (int o = 1; o < 256; o <<= 1) {
        int u = (t >= o) ? sc[t - o] : 0;
        __syncthreads();
        sc[t] += u;
        __syncthreads();
    }
    rs[t] = sc[t] - own;                        // exclusive local start
    const int node = bkt * 256 + t;
    if (node < N) row_ptr[node] = ebase + rs[t];
    if (bkt == nbkt - 1 && t == 0) row_ptr[N] = E;
    __syncthreads();
    if (fits) {
        for (int i = t; i < ecnt; i += 256) {
            uint2 p = pl[i];
            int pos = atomicAdd(&rs[p.y], 1);
            esrc[ebase + pos] = (int)p.x;
        }
    } else {
        for (int i = t; i < ecnt; i += 256) {
            uint2 p = pairs[ebase + i];
            int pos = atomicAdd(&rs[p.y], 1);
            esrc[ebase + pos] = (int)p.x;
        }
    }
}

// ---------------------------------------------------------------------------
// Dense dual GEMM v2: S = H @ Ws (bf16), G = H @ Wn (int8 + row scale).
// Block = 256 thr = 4 waves, 64 rows. Wst+Wnt staged in LDS once per block.
// Wave = (rg: rows 0-31 / 32-63) x (S | G); 2 m-tiles x 8 A-frags held in
// registers (issued upfront, independent), then pure LDS->MFMA stream.
// LDS W reads are same-address broadcasts across the 16 m16-lanes.
// ---------------------------------------------------------------------------
template<int OUTW>
__global__ __launch_bounds__(256)
void sage_gemm(const ushort* __restrict__ Hb,      // [n][128] bf16
               const ushort* __restrict__ Wst,     // [OUTW][128] bf16
               const ushort* __restrict__ Wnt,     // [OUTW][128] bf16
               ushort* __restrict__ S,             // [n][OUTW] bf16
               signed char* __restrict__ Gq,       // [n][OUTW] int8
               float* __restrict__ Gsc,            // [n] fp32
               int n) {
    constexpr int NT = OUTW / 16;                  // 8 or 4
    __shared__ ushort Wl[2][OUTW * 128];

    const int tid  = threadIdx.x;
    const int lane = tid & 63;
    const int wave = tid >> 6;                     // 0..3
    const int rg   = wave >> 1;                    // 0..1 (32-row group)
    const int isG  = wave & 1;
    const int m16  = lane & 15;
    const int kb   = lane >> 4;                    // 0..3
    const int rbase = blockIdx.x * 64 + rg * 32;

    // --- Stage W into LDS (coalesced uint4) ---
    {
        const uint4* s4 = (const uint4*)Wst;
        const uint4* n4 = (const uint4*)Wnt;
        uint4* ls = (uint4*)&Wl[0][0];
        uint4* ln = (uint4*)&Wl[1][0];
#pragma unroll
        for (int j = tid; j < OUTW * 128 / 8; j += 256) {
            ls[j] = s4[j];
            ln[j] = n4[j];
        }
    }

    // --- A fragments: 2 m-tiles x 4 k-chunks, all independent loads ---
    short8 a[2][4];
#pragma unroll
    for (int mt = 0; mt < 2; ++mt) {
        int arow = rbase + mt * 16 + m16;
        if (arow >= n) arow = n - 1;
        const ushort* __restrict__ Ap = &Hb[(size_t)arow * 128 + kb * 8];
#pragma unroll
        for (int c = 0; c < 4; ++c)
            a[mt][c] = *(const short8*)(Ap + c * 32);
    }

    __syncthreads();

    f32x4 acc[2][NT];
#pragma unroll
    for (int mt = 0; mt < 2; ++mt)
#pragma unroll
        for (int t = 0; t < NT; ++t) acc[mt][t] = (f32x4)(0.f);

    const ushort* __restrict__ Wp = &Wl[isG][0];
#pragma unroll
    for (int t = 0; t < NT; ++t) {
#pragma unroll
        for (int c = 0; c < 4; ++c) {
            short8 b = *(const short8*)&Wp[(t * 16 + m16) * 128 + c * 32 + kb * 8];
            acc[0][t] = __builtin_amdgcn_mfma_f32_16x16x32_bf16(a[0][c], b, acc[0][t], 0, 0, 0);
            acc[1][t] = __builtin_amdgcn_mfma_f32_16x16x32_bf16(a[1][c], b, acc[1][t], 0, 0, 0);
        }
    }

    // --- Epilogue: D col = t*16 + m16, row = kb*4 + r ---
#pragma unroll
    for (int mt = 0; mt < 2; ++mt) {
        const int rb = rbase + mt * 16;
        if (!isG) {
#pragma unroll
            for (int r = 0; r < 4; ++r) {
                int row = rb + kb * 4 + r;
                if (row >= n) continue;
#pragma unroll
                for (int t = 0; t < NT; ++t)
                    S[(size_t)row * OUTW + t * 16 + m16] = f2bf(acc[mt][t][r]);
            }
        } else {
#pragma unroll
            for (int r = 0; r < 4; ++r) {
                float mx = 0.f;
#pragma unroll
                for (int t = 0; t < NT; ++t) mx = fmaxf(mx, fabsf(acc[mt][t][r]));
                mx = fmaxf(mx, __shfl_xor(mx, 1));
                mx = fmaxf(mx, __shfl_xor(mx, 2));
                mx = fmaxf(mx, __shfl_xor(mx, 4));
                mx = fmaxf(mx, __shfl_xor(mx, 8));   // 16-lane row max
                int row = rb + kb * 4 + r;
                if (row >= n) continue;
                float inv = (mx > 0.f) ? 127.f / mx : 0.f;
                if (m16 == 0) Gsc[row] = mx * (1.f / 127.f);
#pragma unroll
                for (int t = 0; t < NT; ++t) {
                    int q = (int)rintf(acc[mt][t][r] * inv);
                    q = max(-127, min(127, q));
                    Gq[(size_t)row * OUTW + t * 16 + m16] = (signed char)q;
                }
            }
        }
    }
}

// ---------------------------------------------------------------------------
// Gather-mean over int8 G rows + epilogue.
// ---------------------------------------------------------------------------
__device__ __forceinline__ void acc8(float* af, uint2 v, float sc) {
    af[0] += sc * sb8(v.x, 0); af[1] += sc * sb8(v.x, 1);
    af[2] += sc * sb8(v.x, 2); af[3] += sc * sb8(v.x, 3);
    af[4] += sc * sb8(v.y, 0); af[5] += sc * sb8(v.y, 1);
    af[6] += sc * sb8(v.y, 2); af[7] += sc * sb8(v.y, 3);
}
__device__ __forceinline__ void acc4(float* af, uint v, float sc) {
    af[0] += sc * sb8(v, 0); af[1] += sc * sb8(v, 1);
    af[2] += sc * sb8(v, 2); af[3] += sc * sb8(v, 3);
}

template<int OUTW, bool FINAL>
__global__ __launch_bounds__(256)
void sage_gather(const signed char* __restrict__ Gq, const float* __restrict__ Gsc,
                 const ushort* __restrict__ S, const float* __restrict__ bias,
                 const float* __restrict__ mask,
                 const int* __restrict__ row_ptr, const int* __restrict__ esrc,
                 void* __restrict__ outv, int n) {
    const int lane = threadIdx.x & 63;
    const int wave = threadIdx.x >> 6;     // 0..3
    const int qw   = lane >> 4;
    const int l16  = lane & 15;

#pragma unroll
    for (int j = 0; j < 2; ++j) {
        const int node = blockIdx.x * 32 + (wave * 4 + qw) * 2 + j;
        if (node >= n) continue;
        const int s = row_ptr[node];
        const int e = row_ptr[node + 1];
        const float inv = 1.f / fmaxf((float)(e - s), 1.f);

        if (OUTW == 128) {
            const signed char* __restrict__ gp = Gq + l16 * 8;
            float af[8] = {0.f, 0.f, 0.f, 0.f, 0.f, 0.f, 0.f, 0.f};
            int i = s;
            for (; i + 3 < e; i += 4) {
                int n0 = esrc[i], n1 = esrc[i + 1], n2 = esrc[i + 2], n3 = esrc[i + 3];
                uint2 v0 = *(const uint2*)&gp[(size_t)n0 * 128];
                uint2 v1 = *(const uint2*)&gp[(size_t)n1 * 128];
                uint2 v2 = *(const uint2*)&gp[(size_t)n2 * 128];
                uint2 v3 = *(const uint2*)&gp[(size_t)n3 * 128];
                float c0 = Gsc[n0], c1 = Gsc[n1], c2 = Gsc[n2], c3 = Gsc[n3];
                acc8(af, v0, c0); acc8(af, v1, c1); acc8(af, v2, c2); acc8(af, v3, c3);
            }
            for (; i < e; ++i) {
                int ns = esrc[i];
                uint2 v = *(const uint2*)&gp[(size_t)ns * 128];
                acc8(af, v, Gsc[ns]);
            }
            const int col0 = l16 * 8;
            uint4 sv = *(const uint4*)&S[(size_t)node * 128 + col0];
            float4 b0 = *(const float4*)&bias[col0];
            float4 b1 = *(const float4*)&bias[col0 + 4];
            float z[8];
            z[0] = bf2f(sv.x & 0xffffu) + af[0] * inv + b0.x;
            z[1] = bf2f(sv.x >> 16)     + af[1] * inv + b0.y;
            z[2] = bf2f(sv.y & 0xffffu) + af[2] * inv + b0.z;
            z[3] = bf2f(sv.y >> 16)     + af[3] * inv + b0.w;
            z[4] = bf2f(sv.z & 0xffffu) + af[4] * inv + b1.x;
            z[5] = bf2f(sv.z >> 16)     + af[5] * inv + b1.y;
            z[6] = bf2f(sv.w & 0xffffu) + af[6] * inv + b1.z;
            z[7] = bf2f(sv.w >> 16)     + af[7] * inv + b1.w;
            float4 m0 = *(const float4*)&mask[(size_t)node * 128 + col0];
            float4 m1 = *(const float4*)&mask[(size_t)node * 128 + col0 + 4];
            z[0] = fmaxf(z[0], 0.f) * m0.x; z[1] = fmaxf(z[1], 0.f) * m0.y;
            z[2] = fmaxf(z[2], 0.f) * m0.z; z[3] = fmaxf(z[3], 0.f) * m0.w;
            z[4] = fmaxf(z[4], 0.f) * m1.x; z[5] = fmaxf(z[5], 0.f) * m1.y;
            z[6] = fmaxf(z[6], 0.f) * m1.z; z[7] = fmaxf(z[7], 0.f) * m1.w;
            uint4 pk;
            pk.x = (uint)f2bf(z[0]) | ((uint)f2bf(z[1]) << 16);
            pk.y = (uint)f2bf(z[2]) | ((uint)f2bf(z[3]) << 16);
            pk.z = (uint)f2bf(z[4]) | ((uint)f2bf(z[5]) << 16);
            pk.w = (uint)f2bf(z[6]) | ((uint)f2bf(z[7]) << 16);
            *(uint4*)&((ushort*)outv)[(size_t)node * 128 + col0] = pk;
        } else {  // OUTW == 64, FINAL: fp32 out, no relu/mask
            const signed char* __restrict__ gp = Gq + l16 * 4;
            float af[4] = {0.f, 0.f, 0.f, 0.f};
            int i = s;
            for (; i + 3 < e; i += 4) {
                int n0 = esrc[i], n1 = esrc[i + 1], n2 = esrc[i + 2], n3 = esrc[i + 3];
                uint v0 = *(const uint*)&gp[(size_t)n0 * 64];
                uint v1 = *(const uint*)&gp[(size_t)n1 * 64];
                uint v2 = *(const uint*)&gp[(size_t)n2 * 64];
                uint v3 = *(const uint*)&gp[(size_t)n3 * 64];
                float c0 = Gsc[n0], c1 = Gsc[n1], c2 = Gsc[n2], c3 = Gsc[n3];
                acc4(af, v0, c0); acc4(af, v1, c1); acc4(af, v2, c2); acc4(af, v3, c3);
            }
            for (; i < e; ++i) {
                int ns = esrc[i];
                uint v = *(const uint*)&gp[(size_t)ns * 64];
                acc4(af, v, Gsc[ns]);
            }
            const int col0 = l16 * 4;
            uint2 sv = *(const uint2*)&S[(size_t)node * 64 + col0];
            float4 b0 = *(const float4*)&bias[col0];
            float4 z;
            z.x = bf2f(sv.x & 0xffffu) + af[0] * inv + b0.x;
            z.y = bf2f(sv.x >> 16)     + af[1] * inv + b0.y;
            z.z = bf2f(sv.y & 0xffffu) + af[2] * inv + b0.z;
            z.w = bf2f(sv.y >> 16)     + af[3] * inv + b0.w;
            *(float4*)&((float*)outv)[(size_t)node * 64 + col0] = z;
        }
    }
}

// ---------------------------------------------------------------------------
extern "C" void kernel_launch(void* const* d_in, const int* in_sizes, int n_in,
                              void* d_out, int out_size, void* d_ws, size_t ws_size,
                              hipStream_t stream) {
    const float* x   = (const float*)d_in[0];
    const int*   src = (const int*)d_in[1];
    const int*   dst = (const int*)d_in[2];
    const float* Ws1 = (const float*)d_in[3];
    const float* Wn1 = (const float*)d_in[4];
    const float* b1  = (const float*)d_in[5];
    const float* Ws2 = (const float*)d_in[6];
    const float* Wn2 = (const float*)d_in[7];
    const float* b2  = (const float*)d_in[8];
    const float* Ws3 = (const float*)d_in[9];
    const float* Wn3 = (const float*)d_in[10];
    const float* b3  = (const float*)d_in[11];
    const float* mask1 = (const float*)d_in[12];
    const float* mask2 = (const float*)d_in[13];
    float* out = (float*)d_out;

    const int N = in_sizes[0] / DIN;
    const int E = in_sizes[1];
    const int nbkt = (N + 255) >> 8;            // 196 for N=50000 (<=256)

    // Workspace layout
    char* ws = (char*)d_ws;
    int* bkt_cnt  = (int*)ws;                   // 256
    int* bkt_base = bkt_cnt + 256;              // 256
    int* bkt_cur  = bkt_base + 256;             // 256
    int* row_ptr  = bkt_cur + 256;              // N+1
    int* esrc     = row_ptr + (N + 1);          // E
    size_t off = ((size_t)(768 + N + 1 + E) * sizeof(int) + 255) & ~(size_t)255;
    uint2* pairs = (uint2*)(ws + off);   off += (size_t)E * 8;
    ushort* xb   = (ushort*)(ws + off);  off += (size_t)N * 128 * 2;
    ushort* h1b  = (ushort*)(ws + off);  off += (size_t)N * 128 * 2;
    ushort* h2b  = (ushort*)(ws + off);  off += (size_t)N * 128 * 2;
    ushort* S    = (ushort*)(ws + off);  off += (size_t)N * 128 * 2;
    signed char* Gq = (signed char*)(ws + off); off += (size_t)N * 128;
    float* Gsc   = (float*)(ws + off);   off += (size_t)N * 4;
    ushort* Wst1 = (ushort*)(ws + off);  off += 128 * 128 * 2;
    ushort* Wnt1 = (ushort*)(ws + off);  off += 128 * 128 * 2;
    ushort* Wst2 = (ushort*)(ws + off);  off += 128 * 128 * 2;
    ushort* Wnt2 = (ushort*)(ws + off);  off += 128 * 128 * 2;
    ushort* Wst3 = (ushort*)(ws + off);  off += 64 * 128 * 2;
    ushort* Wnt3 = (ushort*)(ws + off);  off += 64 * 128 * 2;

    const int n4 = N * 128 / 4;
    const int cvtB = (n4 + 255) / 256;
    const int ebB = (E + EB - 1) / EB;

    // --- Prep (cvt + weight transposes) ---
    hipMemsetAsync(bkt_cnt, 0, 256 * sizeof(int), stream);
    prep_all<<<cvtB + 4 * 64 + 2 * 32, 256, 0, stream>>>(
        x, xb, n4, cvtB,
        Ws1, Wn1, Ws2, Wn2, Ws3, Wn3,
        Wst1, Wnt1, Wst2, Wnt2, Wst3, Wnt3);

    // --- Bucketed CSR build ---
    bucket_count<<<ebB, 256, 0, stream>>>(dst, E, bkt_cnt);
    bucket_scan<<<1, 256, 0, stream>>>(bkt_cnt, nbkt, bkt_base, bkt_cur);
    bucket_fill<<<ebB, 256, 0, stream>>>(src, dst, E, bkt_cur, pairs);
    bucket_csr<<<nbkt, 256, 0, stream>>>(pairs, bkt_base, bkt_cnt, row_ptr, esrc, N, E, nbkt);

    const int gemmB = (N + 63) / 64;
    const int gathB = (N + 31) / 32;

    // --- Layer 1 ---
    sage_gemm<128><<<gemmB, 256, 0, stream>>>(xb, Wst1, Wnt1, S, Gq, Gsc, N);
    sage_gather<128, false><<<gathB, 256, 0, stream>>>(Gq, Gsc, S, b1, mask1, row_ptr, esrc, h1b, N);
    // --- Layer 2 ---
    sage_gemm<128><<<gemmB, 256, 0, stream>>>(h1b, Wst2, Wnt2, S, Gq, Gsc, N);
    sage_gather<128, false><<<gathB, 256, 0, stream>>>(Gq, Gsc, S, b2, mask2, row_ptr, esrc, h2b, N);
    // --- Layer 3 ---
    sage_gemm<64><<<gemmB, 256, 0, stream>>>(h2b, Wst3, Wnt3, S, Gq, Gsc, N);
    sage_gather<64, true><<<gathB, 256, 0, stream>>>(Gq, Gsc, S, b3, nullptr, row_ptr, esrc, out, N);
}

// Round 9
// 297.770 us; speedup vs baseline: 1.3886x; 1.0221x over previous
//
#include <hip/hip_runtime.h>
#include <hip/hip_bf16.h>

#define DIN  128
#define DHID 128
#define DOUT 64

typedef short short8 __attribute__((ext_vector_type(8)));
typedef float f32x4  __attribute__((ext_vector_type(4)));

__device__ __forceinline__ ushort f2bf(float f) {
    union { float f; uint u; } c; c.f = f;
    uint u = c.u;
    return (ushort)((u + 0x7fff + ((u >> 16) & 1)) >> 16);   // RNE
}
__device__ __forceinline__ float bf2f(uint h16) {
    union { uint u; float f; } c; c.u = h16 << 16;
    return c.f;
}
// signed byte k of packed uint -> float
__device__ __forceinline__ float sb8(uint u, int k) {
    return (float)((int)(u << (24 - 8 * k)) >> 24);
}

#define EB 4096   // edges per block for count/fill

// ---------------------------------------------------------------------------
// Batched prep: [bucket_count | cvt_bf16 | 6x weight transpose] in one dispatch.
// ---------------------------------------------------------------------------
__device__ __forceinline__ void wprep_dev(const float* __restrict__ W,
                                          ushort* __restrict__ Wt, int OUT, int idx) {
    int nn = idx >> 7;
    int k  = idx & 127;
    Wt[idx] = f2bf(W[(size_t)k * OUT + nn]);   // Wt[n][k] = W[k][n]
}

__global__ __launch_bounds__(256)
void prep_all(const int* __restrict__ dst, int* __restrict__ bkt_cnt, int E, int countB,
              const float* __restrict__ x, ushort* __restrict__ xb, int n4, int cvtB,
              const float* __restrict__ Ws1, const float* __restrict__ Wn1,
              const float* __restrict__ Ws2, const float* __restrict__ Wn2,
              const float* __restrict__ Ws3, const float* __restrict__ Wn3,
              ushort* __restrict__ Wst1, ushort* __restrict__ Wnt1,
              ushort* __restrict__ Wst2, ushort* __restrict__ Wnt2,
              ushort* __restrict__ Wst3, ushort* __restrict__ Wnt3) {
    __shared__ int c[256];
    int b = blockIdx.x;
    const int t = threadIdx.x;
    if (b < countB) {
        c[t] = 0;
        __syncthreads();
        const int base = b * EB;
        const int end = min(base + EB, E);
        for (int i = base + t; i < end; i += 256)
            atomicAdd(&c[dst[i] >> 8], 1);
        __syncthreads();
        int v = c[t];
        if (v) atomicAdd(&bkt_cnt[t], v);
        return;
    }
    b -= countB;
    if (b < cvtB) {
        int i = b * 256 + t;
        if (i < n4) {
            float4 v = ((const float4*)x)[i];
            ushort4 o;
            o.x = f2bf(v.x); o.y = f2bf(v.y); o.z = f2bf(v.z); o.w = f2bf(v.w);
            ((ushort4*)xb)[i] = o;
        }
        return;
    }
    b -= cvtB;
    if (b < 64)  { wprep_dev(Ws1, Wst1, 128, b * 256 + t); return; }
    b -= 64;
    if (b < 64)  { wprep_dev(Wn1, Wnt1, 128, b * 256 + t); return; }
    b -= 64;
    if (b < 64)  { wprep_dev(Ws2, Wst2, 128, b * 256 + t); return; }
    b -= 64;
    if (b < 64)  { wprep_dev(Wn2, Wnt2, 128, b * 256 + t); return; }
    b -= 64;
    if (b < 32)  { wprep_dev(Ws3, Wst3, 64, b * 256 + t); return; }
    b -= 32;
    wprep_dev(Wn3, Wnt3, 64, b * 256 + t);
}

// ---------------------------------------------------------------------------
// Bucketed CSR build (buckets of 256 dst-nodes); per-node lists partitioned
// by src-half (src < N/2 first) so gathers touch an L2-resident half-table.
// ---------------------------------------------------------------------------
__global__ __launch_bounds__(256)
void bucket_scan(const int* __restrict__ bkt_cnt, int nbkt,
                 int* __restrict__ bkt_base, int* __restrict__ bkt_cur) {
    __shared__ int s[256];
    const int t = threadIdx.x;
    int v = (t < nbkt) ? bkt_cnt[t] : 0;
    s[t] = v;
    __syncthreads();
    for (int o = 1; o < 256; o <<= 1) {
        int u = (t >= o) ? s[t - o] : 0;
        __syncthreads();
        s[t] += u;
        __syncthreads();
    }
    if (t < nbkt) { bkt_base[t] = s[t] - v; bkt_cur[t] = s[t] - v; }
}

__global__ __launch_bounds__(256)
void bucket_fill(const int* __restrict__ src, const int* __restrict__ dst, int E,
                 int* __restrict__ bkt_cur, uint2* __restrict__ pairs) {
    __shared__ int c[256];
    __shared__ int startl[256];
    __shared__ int ofs[256];
    const int t = threadIdx.x;
    c[t] = 0;
    __syncthreads();
    const int base = blockIdx.x * EB;
    const int end = min(base + EB, E);
    for (int i = base + t; i < end; i += 256)
        atomicAdd(&c[dst[i] >> 8], 1);
    __syncthreads();
    int v = c[t];
    startl[t] = v ? atomicAdd(&bkt_cur[t], v) : 0;
    ofs[t] = 0;
    __syncthreads();
    for (int i = base + t; i < end; i += 256) {
        int d = dst[i];
        int b = d >> 8;
        int p = startl[b] + atomicAdd(&ofs[b], 1);
        pairs[p] = make_uint2((uint)src[i], (uint)(d & 255));
    }
}

__global__ __launch_bounds__(256)
void bucket_csr(const uint2* __restrict__ pairs, const int* __restrict__ bkt_base,
                const int* __restrict__ bkt_cnt, int* __restrict__ row_ptr,
                int* __restrict__ mid_ptr, int* __restrict__ esrc,
                int N, int E, int nbkt, int half) {
    constexpr int CAP = 6144;                  // 48 KB of pairs
    __shared__ uint2 pl[CAP];
    __shared__ int cnt[512];                   // key = local_dst*2 + src_half
    __shared__ int rs[512];
    __shared__ int sc[256];
    const int bkt = blockIdx.x;
    const int t = threadIdx.x;
    const int ebase = bkt_base[bkt];
    const int ecnt  = bkt_cnt[bkt];
    cnt[t] = 0; cnt[t + 256] = 0;
    __syncthreads();
    const bool fits = (ecnt <= CAP);
    if (fits) {
        for (int i = t; i < ecnt; i += 256) {
            uint2 p = pairs[ebase + i];
            pl[i] = p;
            atomicAdd(&cnt[p.y * 2 + (p.x >= (uint)half)], 1);
        }
    } else {
        for (int i = t; i < ecnt; i += 256) {
            uint2 p = pairs[ebase + i];
            atomicAdd(&cnt[p.y * 2 + (p.x >= (uint)half)], 1);
        }
    }
    __syncthreads();
    int c0 = cnt[2 * t];
    int c1 = cnt[2 * t + 1];
    int pr = c0 + c1;
    sc[t] = pr;
    __syncthreads();
    for (int o = 1; o < 256; o <<= 1) {
        int u = (t >= o) ? sc[t - o] : 0;
        __syncthreads();
        sc[t] += u;
        __syncthreads();
    }
    int excl = sc[t] - pr;                      // exclusive start of this node
    rs[2 * t] = excl;
    rs[2 * t + 1] = excl + c0;
    const int node = bkt * 256 + t;
    if (node < N) {
        row_ptr[node] = ebase + excl;
        mid_ptr[node] = ebase + excl + c0;
    }
    if (bkt == nbkt - 1 && t == 0) row_ptr[N] = E;
    __syncthreads();
    if (fits) {
        for (int i = t; i < ecnt; i += 256) {
            uint2 p = pl[i];
            int pos = atomicAdd(&rs[p.y * 2 + (p.x >= (uint)half)], 1);
            esrc[ebase + pos] = (int)p.x;
        }
    } else {
        for (int i = t; i < ecnt; i += 256) {
            uint2 p = pairs[ebase + i];
            int pos = atomicAdd(&rs[p.y * 2 + (p.x >= (uint)half)], 1);
            esrc[ebase + pos] = (int)p.x;
        }
    }
}

// ---------------------------------------------------------------------------
// Dense dual GEMM: S = H @ Ws (bf16), G = H @ Wn (int8 + row scale).
// Block = 256 thr = 4 waves, 64 rows; Wst+Wnt staged in LDS once per block.
// ---------------------------------------------------------------------------
template<int OUTW>
__global__ __launch_bounds__(256)
void sage_gemm(const ushort* __restrict__ Hb,      // [n][128] bf16
               const ushort* __restrict__ Wst,     // [OUTW][128] bf16
               const ushort* __restrict__ Wnt,     // [OUTW][128] bf16
               ushort* __restrict__ S,             // [n][OUTW] bf16
               signed char* __restrict__ Gq,       // [n][OUTW] int8
               float* __restrict__ Gsc,            // [n] fp32
               int n) {
    constexpr int NT = OUTW / 16;                  // 8 or 4
    __shared__ ushort Wl[2][OUTW * 128];

    const int tid  = threadIdx.x;
    const int lane = tid & 63;
    const int wave = tid >> 6;                     // 0..3
    const int rg   = wave >> 1;                    // 0..1 (32-row group)
    const int isG  = wave & 1;
    const int m16  = lane & 15;
    const int kb   = lane >> 4;                    // 0..3
    const int rbase = blockIdx.x * 64 + rg * 32;

    {
        const uint4* s4 = (const uint4*)Wst;
        const uint4* n4 = (const uint4*)Wnt;
        uint4* ls = (uint4*)&Wl[0][0];
        uint4* ln = (uint4*)&Wl[1][0];
#pragma unroll
        for (int j = tid; j < OUTW * 128 / 8; j += 256) {
            ls[j] = s4[j];
            ln[j] = n4[j];
        }
    }

    short8 a[2][4];
#pragma unroll
    for (int mt = 0; mt < 2; ++mt) {
        int arow = rbase + mt * 16 + m16;
        if (arow >= n) arow = n - 1;
        const ushort* __restrict__ Ap = &Hb[(size_t)arow * 128 + kb * 8];
#pragma unroll
        for (int c = 0; c < 4; ++c)
            a[mt][c] = *(const short8*)(Ap + c * 32);
    }

    __syncthreads();

    f32x4 acc[2][NT];
#pragma unroll
    for (int mt = 0; mt < 2; ++mt)
#pragma unroll
        for (int t = 0; t < NT; ++t) acc[mt][t] = (f32x4)(0.f);

    const ushort* __restrict__ Wp = &Wl[isG][0];
#pragma unroll
    for (int t = 0; t < NT; ++t) {
#pragma unroll
        for (int c = 0; c < 4; ++c) {
            short8 b = *(const short8*)&Wp[(t * 16 + m16) * 128 + c * 32 + kb * 8];
            acc[0][t] = __builtin_amdgcn_mfma_f32_16x16x32_bf16(a[0][c], b, acc[0][t], 0, 0, 0);
            acc[1][t] = __builtin_amdgcn_mfma_f32_16x16x32_bf16(a[1][c], b, acc[1][t], 0, 0, 0);
        }
    }

#pragma unroll
    for (int mt = 0; mt < 2; ++mt) {
        const int rb = rbase + mt * 16;
        if (!isG) {
#pragma unroll
            for (int r = 0; r < 4; ++r) {
                int row = rb + kb * 4 + r;
                if (row >= n) continue;
#pragma unroll
                for (int t = 0; t < NT; ++t)
                    S[(size_t)row * OUTW + t * 16 + m16] = f2bf(acc[mt][t][r]);
            }
        } else {
#pragma unroll
            for (int r = 0; r < 4; ++r) {
                float mx = 0.f;
#pragma unroll
                for (int t = 0; t < NT; ++t) mx = fmaxf(mx, fabsf(acc[mt][t][r]));
                mx = fmaxf(mx, __shfl_xor(mx, 1));
                mx = fmaxf(mx, __shfl_xor(mx, 2));
                mx = fmaxf(mx, __shfl_xor(mx, 4));
                mx = fmaxf(mx, __shfl_xor(mx, 8));   // 16-lane row max
                int row = rb + kb * 4 + r;
                if (row >= n) continue;
                float inv = (mx > 0.f) ? 127.f / mx : 0.f;
                if (m16 == 0) Gsc[row] = mx * (1.f / 127.f);
#pragma unroll
                for (int t = 0; t < NT; ++t) {
                    int q = (int)rintf(acc[mt][t][r] * inv);
                    q = max(-127, min(127, q));
                    Gq[(size_t)row * OUTW + t * 16 + m16] = (signed char)q;
                }
            }
        }
    }
}

// ---------------------------------------------------------------------------
// Gather-mean over int8 G rows + epilogue. Edge lists are pre-partitioned by
// src-half: [s,mid) hits table half 0 (L2-resident), [mid,e) half 1.
// ---------------------------------------------------------------------------
__device__ __forceinline__ void acc8(float* af, uint2 v, float sc) {
    af[0] += sc * sb8(v.x, 0); af[1] += sc * sb8(v.x, 1);
    af[2] += sc * sb8(v.x, 2); af[3] += sc * sb8(v.x, 3);
    af[4] += sc * sb8(v.y, 0); af[5] += sc * sb8(v.y, 1);
    af[6] += sc * sb8(v.y, 2); af[7] += sc * sb8(v.y, 3);
}
__device__ __forceinline__ void acc4(float* af, uint v, float sc) {
    af[0] += sc * sb8(v, 0); af[1] += sc * sb8(v, 1);
    af[2] += sc * sb8(v, 2); af[3] += sc * sb8(v, 3);
}

__device__ __forceinline__ void gath_seg128(const signed char* __restrict__ gp,
                                            const int* __restrict__ esrc,
                                            const float* __restrict__ Gsc,
                                            int s, int e, float* af) {
    int i = s;
    for (; i + 3 < e; i += 4) {
        int n0 = esrc[i], n1 = esrc[i + 1], n2 = esrc[i + 2], n3 = esrc[i + 3];
        uint2 v0 = *(const uint2*)&gp[(size_t)n0 * 128];
        uint2 v1 = *(const uint2*)&gp[(size_t)n1 * 128];
        uint2 v2 = *(const uint2*)&gp[(size_t)n2 * 128];
        uint2 v3 = *(const uint2*)&gp[(size_t)n3 * 128];
        float c0 = Gsc[n0], c1 = Gsc[n1], c2 = Gsc[n2], c3 = Gsc[n3];
        acc8(af, v0, c0); acc8(af, v1, c1); acc8(af, v2, c2); acc8(af, v3, c3);
    }
    for (; i < e; ++i) {
        int ns = esrc[i];
        uint2 v = *(const uint2*)&gp[(size_t)ns * 128];
        acc8(af, v, Gsc[ns]);
    }
}
__device__ __forceinline__ void gath_seg64(const signed char* __restrict__ gp,
                                           const int* __restrict__ esrc,
                                           const float* __restrict__ Gsc,
                                           int s, int e, float* af) {
    int i = s;
    for (; i + 3 < e; i += 4) {
        int n0 = esrc[i], n1 = esrc[i + 1], n2 = esrc[i + 2], n3 = esrc[i + 3];
        uint v0 = *(const uint*)&gp[(size_t)n0 * 64];
        uint v1 = *(const uint*)&gp[(size_t)n1 * 64];
        uint v2 = *(const uint*)&gp[(size_t)n2 * 64];
        uint v3 = *(const uint*)&gp[(size_t)n3 * 64];
        float c0 = Gsc[n0], c1 = Gsc[n1], c2 = Gsc[n2], c3 = Gsc[n3];
        acc4(af, v0, c0); acc4(af, v1, c1); acc4(af, v2, c2); acc4(af, v3, c3);
    }
    for (; i < e; ++i) {
        int ns = esrc[i];
        uint v = *(const uint*)&gp[(size_t)ns * 64];
        acc4(af, v, Gsc[ns]);
    }
}

template<int OUTW, bool FINAL>
__global__ __launch_bounds__(256)
void sage_gather(const signed char* __restrict__ Gq, const float* __restrict__ Gsc,
                 const ushort* __restrict__ S, const float* __restrict__ bias,
                 const float* __restrict__ mask,
                 const int* __restrict__ row_ptr, const int* __restrict__ mid_ptr,
                 const int* __restrict__ esrc,
                 void* __restrict__ outv, int n) {
    const int lane = threadIdx.x & 63;
    const int wave = threadIdx.x >> 6;     // 0..3
    const int qw   = lane >> 4;
    const int l16  = lane & 15;

#pragma unroll
    for (int j = 0; j < 2; ++j) {
        const int node = blockIdx.x * 32 + (wave * 4 + qw) * 2 + j;
        if (node >= n) continue;
        const int s = row_ptr[node];
        const int m = mid_ptr[node];
        const int e = row_ptr[node + 1];
        const float inv = 1.f / fmaxf((float)(e - s), 1.f);

        if (OUTW == 128) {
            const signed char* __restrict__ gp = Gq + l16 * 8;
            float af[8] = {0.f, 0.f, 0.f, 0.f, 0.f, 0.f, 0.f, 0.f};
            gath_seg128(gp, esrc, Gsc, s, m, af);
            gath_seg128(gp, esrc, Gsc, m, e, af);
            const int col0 = l16 * 8;
            uint4 sv = *(const uint4*)&S[(size_t)node * 128 + col0];
            float4 b0 = *(const float4*)&bias[col0];
            float4 b1 = *(const float4*)&bias[col0 + 4];
            float z[8];
            z[0] = bf2f(sv.x & 0xffffu) + af[0] * inv + b0.x;
            z[1] = bf2f(sv.x >> 16)     + af[1] * inv + b0.y;
            z[2] = bf2f(sv.y & 0xffffu) + af[2] * inv + b0.z;
            z[3] = bf2f(sv.y >> 16)     + af[3] * inv + b0.w;
            z[4] = bf2f(sv.z & 0xffffu) + af[4] * inv + b1.x;
            z[5] = bf2f(sv.z >> 16)     + af[5] * inv + b1.y;
            z[6] = bf2f(sv.w & 0xffffu) + af[6] * inv + b1.z;
            z[7] = bf2f(sv.w >> 16)     + af[7] * inv + b1.w;
            float4 m0 = *(const float4*)&mask[(size_t)node * 128 + col0];
            float4 m1 = *(const float4*)&mask[(size_t)node * 128 + col0 + 4];
            z[0] = fmaxf(z[0], 0.f) * m0.x; z[1] = fmaxf(z[1], 0.f) * m0.y;
            z[2] = fmaxf(z[2], 0.f) * m0.z; z[3] = fmaxf(z[3], 0.f) * m0.w;
            z[4] = fmaxf(z[4], 0.f) * m1.x; z[5] = fmaxf(z[5], 0.f) * m1.y;
            z[6] = fmaxf(z[6], 0.f) * m1.z; z[7] = fmaxf(z[7], 0.f) * m1.w;
            uint4 pk;
            pk.x = (uint)f2bf(z[0]) | ((uint)f2bf(z[1]) << 16);
            pk.y = (uint)f2bf(z[2]) | ((uint)f2bf(z[3]) << 16);
            pk.z = (uint)f2bf(z[4]) | ((uint)f2bf(z[5]) << 16);
            pk.w = (uint)f2bf(z[6]) | ((uint)f2bf(z[7]) << 16);
            *(uint4*)&((ushort*)outv)[(size_t)node * 128 + col0] = pk;
        } else {  // OUTW == 64, FINAL: fp32 out, no relu/mask
            const signed char* __restrict__ gp = Gq + l16 * 4;
            float af[4] = {0.f, 0.f, 0.f, 0.f};
            gath_seg64(gp, esrc, Gsc, s, m, af);
            gath_seg64(gp, esrc, Gsc, m, e, af);
            const int col0 = l16 * 4;
            uint2 sv = *(const uint2*)&S[(size_t)node * 64 + col0];
            float4 b0 = *(const float4*)&bias[col0];
            float4 z;
            z.x = bf2f(sv.x & 0xffffu) + af[0] * inv + b0.x;
            z.y = bf2f(sv.x >> 16)     + af[1] * inv + b0.y;
            z.z = bf2f(sv.y & 0xffffu) + af[2] * inv + b0.z;
            z.w = bf2f(sv.y >> 16)     + af[3] * inv + b0.w;
            *(float4*)&((float*)outv)[(size_t)node * 64 + col0] = z;
        }
    }
}

// ---------------------------------------------------------------------------
extern "C" void kernel_launch(void* const* d_in, const int* in_sizes, int n_in,
                              void* d_out, int out_size, void* d_ws, size_t ws_size,
                              hipStream_t stream) {
    const float* x   = (const float*)d_in[0];
    const int*   src = (const int*)d_in[1];
    const int*   dst = (const int*)d_in[2];
    const float* Ws1 = (const float*)d_in[3];
    const float* Wn1 = (const float*)d_in[4];
    const float* b1  = (const float*)d_in[5];
    const float* Ws2 = (const float*)d_in[6];
    const float* Wn2 = (const float*)d_in[7];
    const float* b2  = (const float*)d_in[8];
    const float* Ws3 = (const float*)d_in[9];
    const float* Wn3 = (const float*)d_in[10];
    const float* b3  = (const float*)d_in[11];
    const float* mask1 = (const float*)d_in[12];
    const float* mask2 = (const float*)d_in[13];
    float* out = (float*)d_out;

    const int N = in_sizes[0] / DIN;
    const int E = in_sizes[1];
    const int nbkt = (N + 255) >> 8;            // 196 for N=50000 (<=256)
    const int half = N >> 1;

    // Workspace layout
    char* ws = (char*)d_ws;
    int* bkt_cnt  = (int*)ws;                   // 256
    int* bkt_base = bkt_cnt + 256;              // 256
    int* bkt_cur  = bkt_base + 256;             // 256
    int* row_ptr  = bkt_cur + 256;              // N+1
    int* mid_ptr  = row_ptr + (N + 1);          // N
    int* esrc     = mid_ptr + N;                // E
    size_t off = ((size_t)(768 + 2 * N + 1 + E) * sizeof(int) + 255) & ~(size_t)255;
    uint2* pairs = (uint2*)(ws + off);   off += (size_t)E * 8;
    ushort* xb   = (ushort*)(ws + off);  off += (size_t)N * 128 * 2;
    ushort* h1b  = (ushort*)(ws + off);  off += (size_t)N * 128 * 2;
    ushort* h2b  = (ushort*)(ws + off);  off += (size_t)N * 128 * 2;
    ushort* S    = (ushort*)(ws + off);  off += (size_t)N * 128 * 2;
    signed char* Gq = (signed char*)(ws + off); off += (size_t)N * 128;
    float* Gsc   = (float*)(ws + off);   off += (size_t)N * 4;
    ushort* Wst1 = (ushort*)(ws + off);  off += 128 * 128 * 2;
    ushort* Wnt1 = (ushort*)(ws + off);  off += 128 * 128 * 2;
    ushort* Wst2 = (ushort*)(ws + off);  off += 128 * 128 * 2;
    ushort* Wnt2 = (ushort*)(ws + off);  off += 128 * 128 * 2;
    ushort* Wst3 = (ushort*)(ws + off);  off += 64 * 128 * 2;
    ushort* Wnt3 = (ushort*)(ws + off);  off += 64 * 128 * 2;

    const int n4 = N * 128 / 4;
    const int cvtB = (n4 + 255) / 256;
    const int ebB = (E + EB - 1) / EB;

    // --- Prep (bucket count + cvt + weight transposes, one dispatch) ---
    hipMemsetAsync(bkt_cnt, 0, 256 * sizeof(int), stream);
    prep_all<<<ebB + cvtB + 4 * 64 + 2 * 32, 256, 0, stream>>>(
        dst, bkt_cnt, E, ebB,
        x, xb, n4, cvtB,
        Ws1, Wn1, Ws2, Wn2, Ws3, Wn3,
        Wst1, Wnt1, Wst2, Wnt2, Wst3, Wnt3);

    // --- Bucketed CSR build ---
    bucket_scan<<<1, 256, 0, stream>>>(bkt_cnt, nbkt, bkt_base, bkt_cur);
    bucket_fill<<<ebB, 256, 0, stream>>>(src, dst, E, bkt_cur, pairs);
    bucket_csr<<<nbkt, 256, 0, stream>>>(pairs, bkt_base, bkt_cnt, row_ptr, mid_ptr,
                                         esrc, N, E, nbkt, half);

    const int gemmB = (N + 63) / 64;
    const int gathB = (N + 31) / 32;

    // --- Layer 1 ---
    sage_gemm<128><<<gemmB, 256, 0, stream>>>(xb, Wst1, Wnt1, S, Gq, Gsc, N);
    sage_gather<128, false><<<gathB, 256, 0, stream>>>(Gq, Gsc, S, b1, mask1, row_ptr, mid_ptr, esrc, h1b, N);
    // --- Layer 2 ---
    sage_gemm<128><<<gemmB, 256, 0, stream>>>(h1b, Wst2, Wnt2, S, Gq, Gsc, N);
    sage_gather<128, false><<<gathB, 256, 0, stream>>>(Gq, Gsc, S, b2, mask2, row_ptr, mid_ptr, esrc, h2b, N);
    // --- Layer 3 ---
    sage_gemm<64><<<gemmB, 256, 0, stream>>>(h2b, Wst3, Wnt3, S, Gq, Gsc, N);
    sage_gather<64, true><<<gathB, 256, 0, stream>>>(Gq, Gsc, S, b3, nullptr, row_ptr, mid_ptr, esrc, out, N);
}